// Round 1
// baseline (471.127 us; speedup 1.0000x reference)
//
#include <hip/hip_runtime.h>
#include <stdint.h>

typedef unsigned short u16;
typedef __attribute__((ext_vector_type(8))) short short8;
typedef __attribute__((ext_vector_type(4))) float f32x4;

static constexpr int T_SEQ = 2048;
static constexpr int C_EMB = 768;
static constexpr int N_HD  = 12;
static constexpr int D_HD  = 64;
static constexpr int N_BH  = 48;   // B * H

#define MFMA16(a, b, c) __builtin_amdgcn_mfma_f32_16x16x32_bf16((a), (b), (c), 0, 0, 0)

__device__ __forceinline__ u16 f2bf(float f) {
  union { float f; uint32_t u; } v; v.f = f;
  uint32_t r = v.u + 0x7FFFu + ((v.u >> 16) & 1u);   // round-to-nearest-even
  return (u16)(r >> 16);
}
__device__ __forceinline__ float bf2f(u16 h) {
  union { uint32_t u; float f; } v; v.u = ((uint32_t)h) << 16; return v.f;
}

// async global->LDS, 16 B per lane; lds ptr must be wave-uniform (HW adds lane*16)
__device__ __forceinline__ void gload_lds16(const void* g, void* l) {
  __builtin_amdgcn_global_load_lds((const __attribute__((address_space(1))) void*)g,
                                   (__attribute__((address_space(3))) void*)l, 16, 0, 0);
}

// XOR swizzle for [rows][64 bf16] LDS tiles (128 B rows): conflict-free ds_read_b128
__device__ __forceinline__ int swz(int r, int kb) {
  return r * 128 + (kb ^ ((r & 7) << 4));
}

// ---------------- split fp32 -> bf16 hi/lo ----------------
__global__ void split_kernel(const float* __restrict__ src, u16* __restrict__ hi,
                             u16* __restrict__ lo, int n4) {
  int i = blockIdx.x * blockDim.x + threadIdx.x;
  int stride = gridDim.x * blockDim.x;
  for (; i < n4; i += stride) {
    float4 v = ((const float4*)src)[i];
    ushort4 H, L;
    H.x = f2bf(v.x); L.x = f2bf(v.x - bf2f(H.x));
    H.y = f2bf(v.y); L.y = f2bf(v.y - bf2f(H.y));
    H.z = f2bf(v.z); L.z = f2bf(v.z - bf2f(H.z));
    H.w = f2bf(v.w); L.w = f2bf(v.w - bf2f(H.w));
    ((ushort4*)hi)[i] = H; ((ushort4*)lo)[i] = L;
  }
}

// ---------------- NT GEMM, split-bf16, 128x128 tile, BK=64 ----------------
// D[m,n] = sum_k A[m,k]*B[n,k]  (both row-major, K contiguous)
// EPI 0: QKV epilogue (scatter to q/k/v hi/lo [bh][t][d], q scaled by 0.125)
// EPI 1: plain fp32 write to outp
template <int EPI>
__global__ __launch_bounds__(256, 2) void gemm_nt(
    const u16* __restrict__ Ah, const u16* __restrict__ Al,
    const u16* __restrict__ Bh, const u16* __restrict__ Bl, int K,
    u16* __restrict__ qh, u16* __restrict__ ql,
    u16* __restrict__ kh, u16* __restrict__ kl,
    u16* __restrict__ vh, u16* __restrict__ vl,
    float* __restrict__ outp, int ldout) {
  __shared__ char lds[4 * 16384];   // Ah | Al | Bh | Bl tiles, each 128x64 bf16
  char* LA_h = lds;
  char* LA_l = lds + 16384;
  char* LB_h = lds + 32768;
  char* LB_l = lds + 49152;
  const int tid = threadIdx.x, lane = tid & 63, w = tid >> 6;
  const int g = lane >> 4, c16 = lane & 15;
  const int wr = w >> 1, wc = w & 1;
  const int m0 = blockIdx.y * 128, n0 = blockIdx.x * 128;
  f32x4 acc[4][4] = {};

  for (int k0 = 0; k0 < K; k0 += 64) {
    __syncthreads();
#pragma unroll
    for (int tile = 0; tile < 4; tile++) {
      const u16* src = (tile == 0) ? Ah : (tile == 1) ? Al : (tile == 2) ? Bh : Bl;
      const int row0 = (tile < 2) ? m0 : n0;
      char* dst = lds + tile * 16384;
#pragma unroll
      for (int i = 0; i < 4; i++) {
        int c = tid + 256 * i;            // 16-B chunk id; dest byte = c*16
        int r = c >> 3;                   // 8 chunks per 128-B row
        int sp = (c & 7) ^ (r & 7);       // pre-swizzled source slot
        gload_lds16(src + (size_t)(row0 + r) * K + k0 + sp * 8,
                    dst + (tid >> 6) * 1024 + i * 4096);
      }
    }
    __syncthreads();
#pragma unroll
    for (int ks = 0; ks < 2; ks++) {
      const int kb = ks * 64 + g * 16;
      short8 aH[4], aL[4], bH[4], bL[4];
#pragma unroll
      for (int mf = 0; mf < 4; mf++) {
        int r = wr * 64 + mf * 16 + c16;
        aH[mf] = *(const short8*)(LA_h + swz(r, kb));
        aL[mf] = *(const short8*)(LA_l + swz(r, kb));
      }
#pragma unroll
      for (int nf = 0; nf < 4; nf++) {
        int r = wc * 64 + nf * 16 + c16;
        bH[nf] = *(const short8*)(LB_h + swz(r, kb));
        bL[nf] = *(const short8*)(LB_l + swz(r, kb));
      }
#pragma unroll
      for (int mf = 0; mf < 4; mf++)
#pragma unroll
        for (int nf = 0; nf < 4; nf++) {
          acc[mf][nf] = MFMA16(aH[mf], bH[nf], acc[mf][nf]);
          acc[mf][nf] = MFMA16(aH[mf], bL[nf], acc[mf][nf]);
          acc[mf][nf] = MFMA16(aL[mf], bH[nf], acc[mf][nf]);
        }
    }
  }

#pragma unroll
  for (int mf = 0; mf < 4; mf++)
#pragma unroll
    for (int nf = 0; nf < 4; nf++)
#pragma unroll
      for (int j = 0; j < 4; j++) {
        int row = m0 + wr * 64 + mf * 16 + g * 4 + j;
        int col = n0 + wc * 64 + nf * 16 + c16;
        float val = acc[mf][nf][j];
        if (EPI == 0) {
          int b = row >> 11, t = row & (T_SEQ - 1);
          int p = (col >= 2 * C_EMB) ? 2 : (col >= C_EMB ? 1 : 0);
          int rem = col - p * C_EMB;
          int h = rem >> 6, d = rem & 63;
          if (p == 0) val *= 0.125f;     // fold 1/sqrt(D) into Q
          u16 hv = f2bf(val);
          u16 lv = f2bf(val - bf2f(hv));
          size_t idx = ((size_t)(b * N_HD + h) * T_SEQ + t) * D_HD + d;
          u16* dh = (p == 0) ? qh : (p == 1) ? kh : vh;
          u16* dl = (p == 0) ? ql : (p == 1) ? kl : vl;
          dh[idx] = hv; dl[idx] = lv;
        } else {
          outp[(size_t)row * ldout + col] = val;
        }
      }
}

// ---------------- V transpose: [bh][t][d] -> [bh][d][t] (hi and lo) ----------------
__global__ void transpose_v(const u16* __restrict__ vh, const u16* __restrict__ vl,
                            u16* __restrict__ vth, u16* __restrict__ vtl) {
  __shared__ u16 th[64][65];
  __shared__ u16 tl[64][65];
  const int bh = blockIdx.y;
  const int t0 = blockIdx.x * 64;
  const int tid = threadIdx.x;
  {
    const int r = tid >> 2, c0 = (tid & 3) * 16;
    const u16* s0 = vh + ((size_t)bh * T_SEQ + t0 + r) * D_HD + c0;
    const u16* s1 = vl + ((size_t)bh * T_SEQ + t0 + r) * D_HD + c0;
#pragma unroll
    for (int i = 0; i < 16; i++) { th[r][c0 + i] = s0[i]; tl[r][c0 + i] = s1[i]; }
  }
  __syncthreads();
  {
    const int d = tid >> 2, k0 = (tid & 3) * 16;
    u16* d0 = vth + ((size_t)bh * D_HD + d) * T_SEQ + t0 + k0;
    u16* d1 = vtl + ((size_t)bh * D_HD + d) * T_SEQ + t0 + k0;
#pragma unroll
    for (int i = 0; i < 16; i++) { d0[i] = th[k0 + i][d]; d1[i] = tl[k0 + i][d]; }
  }
}

// ---------------- flash attention, split-bf16, fp32 online softmax ----------------
// grid: (T/128 q-blocks, 48 bh); 4 waves x 32 q-rows each; KV tiles of 64
__global__ __launch_bounds__(256, 2) void fa_kernel(
    const u16* __restrict__ qh, const u16* __restrict__ ql,
    const u16* __restrict__ kh, const u16* __restrict__ kl,
    const u16* __restrict__ vth, const u16* __restrict__ vtl,
    u16* __restrict__ yh, u16* __restrict__ yl) {
  __shared__ char lds[32768 + 4 * 4608];  // Kh|Kl|Vh|Vl (8KB each) + per-wave P [32][72]
  char* LK_h = lds;
  char* LK_l = lds + 8192;
  char* LV_h = lds + 16384;
  char* LV_l = lds + 24576;
  const int tid = threadIdx.x, lane = tid & 63, w = tid >> 6;
  const int g = lane >> 4, c16 = lane & 15;
  u16* P = (u16*)(lds + 32768 + w * 4608);   // per-wave private, stride 72 u16 (144 B)
  const int bh = blockIdx.y, qb = blockIdx.x;

  // hoist Q fragments (already scaled by 1/8)
  const size_t qoff = ((size_t)bh * T_SEQ + qb * 128 + w * 32) * D_HD;
  short8 qH[2][2], qL[2][2];
#pragma unroll
  for (int rf = 0; rf < 2; rf++)
#pragma unroll
    for (int ks = 0; ks < 2; ks++) {
      size_t o = qoff + (size_t)(rf * 16 + c16) * D_HD + ks * 32 + g * 8;
      qH[rf][ks] = *(const short8*)(qh + o);
      qL[rf][ks] = *(const short8*)(ql + o);
    }

  f32x4 yac[2][4] = {};
  float m_r[2][4], l_r[2][4];
#pragma unroll
  for (int rf = 0; rf < 2; rf++)
#pragma unroll
    for (int j = 0; j < 4; j++) { m_r[rf][j] = -1e30f; l_r[rf][j] = 0.f; }

  const size_t kbase = (size_t)bh * T_SEQ * D_HD;
  const size_t vbase = (size_t)bh * D_HD * T_SEQ;

  for (int kt = 0; kt < T_SEQ / 64; kt++) {
    const int kv0 = kt * 64;
    __syncthreads();
#pragma unroll
    for (int i = 0; i < 2; i++) {
      int c = tid + 256 * i;
      int r = c >> 3;
      int sp = (c & 7) ^ (r & 7);
      int lo = (tid >> 6) * 1024 + i * 4096;
      gload_lds16(kh + kbase + (size_t)(kv0 + r) * D_HD + sp * 8, LK_h + lo);
      gload_lds16(kl + kbase + (size_t)(kv0 + r) * D_HD + sp * 8, LK_l + lo);
      gload_lds16(vth + vbase + (size_t)r * T_SEQ + kv0 + sp * 8, LV_h + lo);
      gload_lds16(vtl + vbase + (size_t)r * T_SEQ + kv0 + sp * 8, LV_l + lo);
    }
    __syncthreads();

    // scores S = (Q/8) K^T  -> rows q, cols kv
    f32x4 sac[2][4] = {};
#pragma unroll
    for (int ks = 0; ks < 2; ks++) {
      const int kb = ks * 64 + g * 16;
      short8 kH[4], kL[4];
#pragma unroll
      for (int nf = 0; nf < 4; nf++) {
        int r = nf * 16 + c16;
        kH[nf] = *(const short8*)(LK_h + swz(r, kb));
        kL[nf] = *(const short8*)(LK_l + swz(r, kb));
      }
#pragma unroll
      for (int rf = 0; rf < 2; rf++)
#pragma unroll
        for (int nf = 0; nf < 4; nf++) {
          sac[rf][nf] = MFMA16(qH[rf][ks], kH[nf], sac[rf][nf]);
          sac[rf][nf] = MFMA16(qH[rf][ks], kL[nf], sac[rf][nf]);
          sac[rf][nf] = MFMA16(qL[rf][ks], kH[nf], sac[rf][nf]);
        }
    }

    // online softmax (fp32). row r = rf*16 + g*4 + j lives in 16 lanes (same g).
    float pv[2][4][4];
#pragma unroll
    for (int rf = 0; rf < 2; rf++)
#pragma unroll
      for (int j = 0; j < 4; j++) {
        float mx = fmaxf(fmaxf(sac[rf][0][j], sac[rf][1][j]),
                         fmaxf(sac[rf][2][j], sac[rf][3][j]));
#pragma unroll
        for (int dd = 1; dd < 16; dd <<= 1) mx = fmaxf(mx, __shfl_xor(mx, dd));
        float mo = m_r[rf][j];
        float mn = fmaxf(mo, mx);
        float sc = __expf(mo - mn);
        float rs = 0.f;
#pragma unroll
        for (int nf = 0; nf < 4; nf++) {
          float e = __expf(sac[rf][nf][j] - mn);
          pv[rf][nf][j] = e; rs += e;
        }
#pragma unroll
        for (int dd = 1; dd < 16; dd <<= 1) rs += __shfl_xor(rs, dd);
        m_r[rf][j] = mn;
        l_r[rf][j] = l_r[rf][j] * sc + rs;
#pragma unroll
        for (int nf = 0; nf < 4; nf++) yac[rf][nf][j] *= sc;
      }

    // stage P-hi through per-wave LDS, grab A-frags; then P-lo (same buffer)
#pragma unroll
    for (int rf = 0; rf < 2; rf++)
#pragma unroll
      for (int nf = 0; nf < 4; nf++)
#pragma unroll
        for (int j = 0; j < 4; j++)
          P[(rf * 16 + g * 4 + j) * 72 + nf * 16 + c16] = f2bf(pv[rf][nf][j]);
    short8 paH[2][2];
#pragma unroll
    for (int rf = 0; rf < 2; rf++)
#pragma unroll
      for (int ks = 0; ks < 2; ks++)
        paH[rf][ks] = *(const short8*)((char*)P + (rf * 16 + c16) * 144 + ks * 64 + g * 16);
#pragma unroll
    for (int rf = 0; rf < 2; rf++)
#pragma unroll
      for (int nf = 0; nf < 4; nf++)
#pragma unroll
        for (int j = 0; j < 4; j++) {
          float e = pv[rf][nf][j];
          P[(rf * 16 + g * 4 + j) * 72 + nf * 16 + c16] = f2bf(e - bf2f(f2bf(e)));
        }
    short8 paL[2][2];
#pragma unroll
    for (int rf = 0; rf < 2; rf++)
#pragma unroll
      for (int ks = 0; ks < 2; ks++)
        paL[rf][ks] = *(const short8*)((char*)P + (rf * 16 + c16) * 144 + ks * 64 + g * 16);

    // PV: y += P V   (B-frags from transposed V)
#pragma unroll
    for (int ks = 0; ks < 2; ks++) {
      const int kb = ks * 64 + g * 16;
      short8 vH[4], vL[4];
#pragma unroll
      for (int nf = 0; nf < 4; nf++) {
        int r = nf * 16 + c16;
        vH[nf] = *(const short8*)(LV_h + swz(r, kb));
        vL[nf] = *(const short8*)(LV_l + swz(r, kb));
      }
#pragma unroll
      for (int rf = 0; rf < 2; rf++)
#pragma unroll
        for (int nf = 0; nf < 4; nf++) {
          yac[rf][nf] = MFMA16(paH[rf][ks], vH[nf], yac[rf][nf]);
          yac[rf][nf] = MFMA16(paH[rf][ks], vL[nf], yac[rf][nf]);
          yac[rf][nf] = MFMA16(paL[rf][ks], vH[nf], yac[rf][nf]);
        }
    }
  }

  // epilogue: y /= l, split hi/lo, write [b][t][C] at head offset
  const int b = bh / N_HD, hh = bh % N_HD;
#pragma unroll
  for (int rf = 0; rf < 2; rf++)
#pragma unroll
    for (int nf = 0; nf < 4; nf++)
#pragma unroll
      for (int j = 0; j < 4; j++) {
        int t = qb * 128 + w * 32 + rf * 16 + g * 4 + j;
        int d = nf * 16 + c16;
        float v = yac[rf][nf][j] / l_r[rf][j];
        size_t idx = ((size_t)b * T_SEQ + t) * C_EMB + hh * D_HD + d;
        u16 hv = f2bf(v);
        yh[idx] = hv; yl[idx] = f2bf(v - bf2f(hv));
      }
}

// ---------------- launch ----------------
extern "C" void kernel_launch(void* const* d_in, const int* in_sizes, int n_in,
                              void* d_out, int out_size, void* d_ws, size_t ws_size,
                              hipStream_t stream) {
  (void)in_sizes; (void)n_in; (void)out_size;
  const float* x      = (const float*)d_in[0];
  const float* w_attn = (const float*)d_in[1];
  const float* w_proj = (const float*)d_in[2];
  float* out = (float*)d_out;

  const size_t NX  = (size_t)4 * T_SEQ * C_EMB;     // 6,291,456
  const size_t NWA = (size_t)3 * C_EMB * C_EMB;     // 1,769,472
  const size_t NWP = (size_t)C_EMB * C_EMB;         //   589,824
  const size_t NQ  = (size_t)N_BH * T_SEQ * D_HD;   // 6,291,456

  u16* ws = (u16*)d_ws;
  size_t off = 0;
  u16* XH  = ws + off; off += NX;   u16* XL  = ws + off; off += NX;
  u16* WAH = ws + off; off += NWA;  u16* WAL = ws + off; off += NWA;
  u16* WPH = ws + off; off += NWP;  u16* WPL = ws + off; off += NWP;
  u16* QH  = ws + off; off += NQ;   u16* QL  = ws + off; off += NQ;
  u16* KH  = ws + off; off += NQ;   u16* KL  = ws + off; off += NQ;
  u16* VH  = ws + off; off += NQ;   u16* VL  = ws + off; off += NQ;
  u16* VTH = ws + off; off += NQ;   u16* VTL = ws + off; off += NQ;
  u16* YH  = ws + off; off += NX;   u16* YL  = ws + off; off += NX;
  if (ws_size < off * sizeof(u16)) return;  // workspace too small: fail loudly (poisoned out)

  auto blks = [](size_t n4) {
    size_t b = (n4 + 255) / 256; return (unsigned)(b > 2048 ? 2048 : b);
  };
  split_kernel<<<blks(NX / 4), 256, 0, stream>>>(x, XH, XL, (int)(NX / 4));
  split_kernel<<<blks(NWA / 4), 256, 0, stream>>>(w_attn, WAH, WAL, (int)(NWA / 4));
  split_kernel<<<blks(NWP / 4), 256, 0, stream>>>(w_proj, WPH, WPL, (int)(NWP / 4));

  gemm_nt<0><<<dim3(3 * C_EMB / 128, 4 * T_SEQ / 128), 256, 0, stream>>>(
      XH, XL, WAH, WAL, C_EMB, QH, QL, KH, KL, VH, VL, nullptr, 0);

  transpose_v<<<dim3(T_SEQ / 64, N_BH), 256, 0, stream>>>(VH, VL, VTH, VTL);

  fa_kernel<<<dim3(T_SEQ / 128, N_BH), 256, 0, stream>>>(QH, QL, KH, KL, VTH, VTL, YH, YL);

  gemm_nt<1><<<dim3(C_EMB / 128, 4 * T_SEQ / 128), 256, 0, stream>>>(
      YH, YL, WPH, WPL, C_EMB, nullptr, nullptr, nullptr, nullptr, nullptr, nullptr,
      out, C_EMB);
}

// Round 2
// 289.907 us; speedup vs baseline: 1.6251x; 1.6251x over previous
//
#include <hip/hip_runtime.h>
#include <stdint.h>

typedef unsigned short u16;
typedef uint32_t u32;
typedef __attribute__((ext_vector_type(8))) short short8;
typedef __attribute__((ext_vector_type(4))) float f32x4;
typedef __attribute__((ext_vector_type(16))) float f32x16;

static constexpr int T_SEQ = 2048;
static constexpr int C_EMB = 768;
static constexpr int N_HD  = 12;
static constexpr int D_HD  = 64;
static constexpr int N_BH  = 48;   // B * H

#define MFMA16(a, b, c) __builtin_amdgcn_mfma_f32_16x16x32_bf16((a), (b), (c), 0, 0, 0)
#define MFMA32(a, b, c) __builtin_amdgcn_mfma_f32_32x32x16_bf16((a), (b), (c), 0, 0, 0)

__device__ __forceinline__ u16 f2bf(float f) {
  union { float f; u32 u; } v; v.f = f;
  u32 r = v.u + 0x7FFFu + ((v.u >> 16) & 1u);   // RNE
  return (u16)(r >> 16);
}
__device__ __forceinline__ float bf2f(u16 h) {
  union { u32 u; float f; } v; v.u = ((u32)h) << 16; return v.f;
}

__device__ __forceinline__ void gload_lds16(const void* g, void* l) {
  __builtin_amdgcn_global_load_lds((const __attribute__((address_space(1))) void*)g,
                                   (__attribute__((address_space(3))) void*)l, 16, 0, 0);
}

// XOR swizzle for [rows][64 bf16] LDS tiles (128 B rows, 8 slots of 16 B)
__device__ __forceinline__ int swz(int r, int kb) {
  return r * 128 + (kb ^ ((r & 7) << 4));
}

// ---------------- split fp32 -> bf16 hi (+ optional lo) ----------------
__global__ void split_kernel(const float* __restrict__ src, u16* __restrict__ hi,
                             u16* __restrict__ lo, int n4) {
  int i = blockIdx.x * blockDim.x + threadIdx.x;
  int stride = gridDim.x * blockDim.x;
  for (; i < n4; i += stride) {
    float4 v = ((const float4*)src)[i];
    ushort4 H;
    H.x = f2bf(v.x); H.y = f2bf(v.y); H.z = f2bf(v.z); H.w = f2bf(v.w);
    ((ushort4*)hi)[i] = H;
    if (lo) {
      ushort4 L;
      L.x = f2bf(v.x - bf2f(H.x)); L.y = f2bf(v.y - bf2f(H.y));
      L.z = f2bf(v.z - bf2f(H.z)); L.w = f2bf(v.w - bf2f(H.w));
      ((ushort4*)lo)[i] = L;
    }
  }
}

// ---------------- NT GEMM, split-bf16, 128x128 tile, BK=64 ----------------
// D[m,n] = sum_k A[m,k]*B[n,k]
// PASSES==3: aH*bH + aH*bL + aL*bH ; PASSES==2: aH*bH + aL*bH (no B-lo)
// EPI 0: QKV epilogue -> q,k bf16 [bh][t][64] (q*0.125), v bf16 transposed [bh][d][2048]
// EPI 1: fp32 write to outp
template <int EPI, int PASSES>
__global__ __launch_bounds__(256, 2) void gemm_nt(
    const u16* __restrict__ Ah, const u16* __restrict__ Al,
    const u16* __restrict__ Bh, const u16* __restrict__ Bl, int K,
    u16* __restrict__ qg, u16* __restrict__ kg, u16* __restrict__ vtg,
    float* __restrict__ outp, int ldout) {
  constexpr int NT = (PASSES == 2) ? 3 : 4;
  __shared__ __align__(16) char lds[NT * 16384];   // Ah | Al | Bh | [Bl]
  char* LA_h = lds;
  char* LA_l = lds + 16384;
  char* LB_h = lds + 32768;
  char* LB_l = lds + ((NT == 4) ? 49152 : 32768);
  const int tid = threadIdx.x, lane = tid & 63, w = tid >> 6;
  const int g = lane >> 4, c16 = lane & 15;
  const int wr = w >> 1, wc = w & 1;
  const int m0 = blockIdx.y * 128, n0 = blockIdx.x * 128;
  f32x4 acc[4][4] = {};

  for (int k0 = 0; k0 < K; k0 += 64) {
    __syncthreads();
#pragma unroll
    for (int tile = 0; tile < NT; tile++) {
      const u16* src = (tile == 0) ? Ah : (tile == 1) ? Al : (tile == 2) ? Bh : Bl;
      const int row0 = (tile < 2) ? m0 : n0;
      char* dst = lds + tile * 16384;
#pragma unroll
      for (int i = 0; i < 4; i++) {
        int c = tid + 256 * i;
        int r = c >> 3;
        int sp = (c & 7) ^ (r & 7);
        gload_lds16(src + (size_t)(row0 + r) * K + k0 + sp * 8,
                    dst + w * 1024 + i * 4096);
      }
    }
    __syncthreads();
#pragma unroll
    for (int ks = 0; ks < 2; ks++) {
      const int kb = ks * 64 + g * 16;
      short8 aH[4], aL[4], bH[4], bL[4];
#pragma unroll
      for (int mf = 0; mf < 4; mf++) {
        int r = wr * 64 + mf * 16 + c16;
        aH[mf] = *(const short8*)(LA_h + swz(r, kb));
        aL[mf] = *(const short8*)(LA_l + swz(r, kb));
      }
#pragma unroll
      for (int nf = 0; nf < 4; nf++) {
        int r = wc * 64 + nf * 16 + c16;
        bH[nf] = *(const short8*)(LB_h + swz(r, kb));
        if (PASSES == 3) bL[nf] = *(const short8*)(LB_l + swz(r, kb));
      }
#pragma unroll
      for (int mf = 0; mf < 4; mf++)
#pragma unroll
        for (int nf = 0; nf < 4; nf++) {
          acc[mf][nf] = MFMA16(aH[mf], bH[nf], acc[mf][nf]);
          acc[mf][nf] = MFMA16(aL[mf], bH[nf], acc[mf][nf]);
          if (PASSES == 3) acc[mf][nf] = MFMA16(aH[mf], bL[nf], acc[mf][nf]);
        }
    }
  }

#pragma unroll
  for (int mf = 0; mf < 4; mf++)
#pragma unroll
    for (int nf = 0; nf < 4; nf++) {
      if (EPI == 0) {
        int col = n0 + wc * 64 + nf * 16 + c16;
        int p = (col >= 2 * C_EMB) ? 2 : (col >= C_EMB ? 1 : 0);
        int rem = col - p * C_EMB;
        int h = rem >> 6, d = rem & 63;
        int rowb = m0 + wr * 64 + mf * 16 + g * 4;
        int b = rowb >> 11, t0 = rowb & (T_SEQ - 1);
        int bhh = b * N_HD + h;
        if (p == 2) {
          ushort4 V4;
#pragma unroll
          for (int jj = 0; jj < 4; jj++) (&V4.x)[jj] = f2bf(acc[mf][nf][jj]);
          *(ushort4*)(vtg + ((size_t)bhh * D_HD + d) * T_SEQ + t0) = V4;
        } else {
          u16* dst = (p == 0) ? qg : kg;
          float scl = (p == 0) ? 0.125f : 1.0f;
#pragma unroll
          for (int jj = 0; jj < 4; jj++)
            dst[((size_t)bhh * T_SEQ + t0 + jj) * D_HD + d] = f2bf(acc[mf][nf][jj] * scl);
        }
      } else {
#pragma unroll
        for (int jj = 0; jj < 4; jj++) {
          int row = m0 + wr * 64 + mf * 16 + g * 4 + jj;
          int col = n0 + wc * 64 + nf * 16 + c16;
          outp[(size_t)row * ldout + col] = acc[mf][nf][jj];
        }
      }
    }
}

// ---------------- flash attention: swapped QK^T, 32x32x16, single bf16 ----------------
// grid (T/128, 48); 4 waves x 32 q-rows. KV tile = 128. Lane owns q = lane&31.
__global__ __launch_bounds__(256, 3) void fa_kernel(
    const u16* __restrict__ qg, const u16* __restrict__ kg,
    const u16* __restrict__ vtg, u16* __restrict__ yh, u16* __restrict__ yl) {
  __shared__ __align__(16) char lds[32768];   // K[128][64] swz | V^T[64][128] swz
  char* LK = lds;
  char* LV = lds + 16384;
  const int tid = threadIdx.x, lane = tid & 63, w = tid >> 6;
  const int r31 = lane & 31, hi = lane >> 5;
  const int bh = blockIdx.y, qb = blockIdx.x;
  const size_t kvbase = (size_t)bh * T_SEQ * D_HD;

  // Q B-frags (q pre-scaled by 1/8): q row = qb*128 + w*32 + r31, k = ks*16 + hi*8
  const u16* qrow = qg + kvbase + (size_t)(qb * 128 + w * 32 + r31) * D_HD + hi * 8;
  short8 qf[4];
#pragma unroll
  for (int ks = 0; ks < 4; ks++) qf[ks] = *(const short8*)(qrow + ks * 16);

  f32x16 yac[2] = {};
  float m_run = -1e30f, l_run = 0.f;

  for (int kt = 0; kt < T_SEQ / 128; kt++) {
    const int kv0 = kt * 128;
    __syncthreads();
#pragma unroll
    for (int i = 0; i < 4; i++) {
      int c = tid + 256 * i;
      int kr = c >> 3, ksl = (c & 7) ^ (kr & 7);
      gload_lds16(kg + kvbase + (size_t)(kv0 + kr) * D_HD + ksl * 8,
                  LK + w * 1024 + i * 4096);
      int vd = c >> 4, vsl = (c & 15) ^ (vd & 15);
      gload_lds16(vtg + kvbase + (size_t)vd * T_SEQ + kv0 + vsl * 8,
                  LV + w * 1024 + i * 4096);
    }
    __syncthreads();

    // S^T = mfma(K, Q): rows kv, cols q. sA[nb]: kv = nb*32 + (reg&3)+8*(reg>>2)+4*hi
    f32x16 sA[4];
#pragma unroll
    for (int nb = 0; nb < 4; nb++) {
      f32x16 s = {};
#pragma unroll
      for (int ks = 0; ks < 4; ks++) {
        int row = nb * 32 + r31;
        short8 kf = *(const short8*)(LK + row * 128 + (((2 * ks + hi) ^ (row & 7)) << 4));
        s = MFMA32(kf, qf[ks], s);
      }
      sA[nb] = s;
    }

    // online softmax: all state lane-local (q = lane&31); combine halves via 1 shfl
    float mloc = -1e30f;
#pragma unroll
    for (int nb = 0; nb < 4; nb++)
#pragma unroll
      for (int rr = 0; rr < 16; rr++) mloc = fmaxf(mloc, sA[nb][rr]);
    mloc = fmaxf(mloc, __shfl_xor(mloc, 32));
    float mn = fmaxf(m_run, mloc);
    float sc = __expf(m_run - mn);
    float rs = 0.f;
#pragma unroll
    for (int nb = 0; nb < 4; nb++)
#pragma unroll
      for (int rr = 0; rr < 16; rr++) {
        float p = __expf(sA[nb][rr] - mn);
        sA[nb][rr] = p; rs += p;
      }
    rs += __shfl_xor(rs, 32);
    l_run = l_run * sc + rs;
    m_run = mn;
    yac[0] = yac[0] * sc;
    yac[1] = yac[1] * sc;

    // P -> bf16 B-frags via register exchange; PV: y^T = mfma(V^T, P)
#pragma unroll
    for (int nb = 0; nb < 4; nb++) {
      u32 wd[8], od[8];
#pragma unroll
      for (int s = 0; s < 4; s++)
#pragma unroll
        for (int t = 0; t < 2; t++)
          wd[s * 2 + t] = (u32)f2bf(sA[nb][s * 4 + t * 2]) |
                          ((u32)f2bf(sA[nb][s * 4 + t * 2 + 1]) << 16);
#pragma unroll
      for (int q = 0; q < 8; q++) od[q] = (u32)__shfl_xor((int)wd[q], 32);
#pragma unroll
      for (int q4 = 0; q4 < 2; q4++) {
        // B-frag for kv step kk = nb*2+q4: words cover kv = kk*16 + hi*8 + {0..7}
        u32 b0 = hi ? od[(q4 * 2 + 1) * 2 + 0] : wd[(q4 * 2 + 0) * 2 + 0];
        u32 b1 = hi ? od[(q4 * 2 + 1) * 2 + 1] : wd[(q4 * 2 + 0) * 2 + 1];
        u32 b2 = hi ? wd[(q4 * 2 + 1) * 2 + 0] : od[(q4 * 2 + 0) * 2 + 0];
        u32 b3 = hi ? wd[(q4 * 2 + 1) * 2 + 1] : od[(q4 * 2 + 0) * 2 + 1];
        union { u32 u[4]; short8 s8; } pu;
        pu.u[0] = b0; pu.u[1] = b1; pu.u[2] = b2; pu.u[3] = b3;
        const int kk = nb * 2 + q4;
#pragma unroll
        for (int nd = 0; nd < 2; nd++) {
          int d = nd * 32 + r31;
          short8 vf = *(const short8*)(LV + d * 256 + (((2 * kk + hi) ^ (d & 15)) << 4));
          yac[nd] = MFMA32(vf, pu.s8, yac[nd]);
        }
      }
    }
  }

  // epilogue: y^T frags: rows d, cols q(=lane&31); divide by l, split hi/lo
  float inv = 1.0f / l_run;
  const int b = bh / N_HD, hh = bh % N_HD;
  const int t = qb * 128 + w * 32 + r31;
  const size_t ybase = ((size_t)b * T_SEQ + t) * C_EMB + hh * D_HD;
#pragma unroll
  for (int nd = 0; nd < 2; nd++)
#pragma unroll
    for (int rq = 0; rq < 4; rq++) {
      int d0 = nd * 32 + rq * 8 + hi * 4;
      ushort4 H, L;
#pragma unroll
      for (int jj = 0; jj < 4; jj++) {
        float v = yac[nd][rq * 4 + jj] * inv;
        u16 hv = f2bf(v);
        (&H.x)[jj] = hv;
        (&L.x)[jj] = f2bf(v - bf2f(hv));
      }
      *(ushort4*)(yh + ybase + d0) = H;
      *(ushort4*)(yl + ybase + d0) = L;
    }
}

// ---------------- launch ----------------
extern "C" void kernel_launch(void* const* d_in, const int* in_sizes, int n_in,
                              void* d_out, int out_size, void* d_ws, size_t ws_size,
                              hipStream_t stream) {
  (void)in_sizes; (void)n_in; (void)out_size;
  const float* x      = (const float*)d_in[0];
  const float* w_attn = (const float*)d_in[1];
  const float* w_proj = (const float*)d_in[2];
  float* out = (float*)d_out;

  const size_t NX  = (size_t)4 * T_SEQ * C_EMB;     // 6,291,456
  const size_t NWA = (size_t)3 * C_EMB * C_EMB;
  const size_t NWP = (size_t)C_EMB * C_EMB;
  const size_t NQ  = (size_t)N_BH * T_SEQ * D_HD;

  u16* ws = (u16*)d_ws;
  size_t off = 0;
  u16* XH  = ws + off; off += NX;   u16* XL  = ws + off; off += NX;
  u16* WAH = ws + off; off += NWA;
  u16* WPH = ws + off; off += NWP;  u16* WPL = ws + off; off += NWP;
  u16* QB  = ws + off; off += NQ;
  u16* KB  = ws + off; off += NQ;
  u16* VT  = ws + off; off += NQ;
  u16* YH  = ws + off; off += NX;   u16* YL  = ws + off; off += NX;
  if (ws_size < off * sizeof(u16)) return;

  auto blks = [](size_t n4) {
    size_t b = (n4 + 255) / 256; return (unsigned)(b > 2048 ? 2048 : b);
  };
  split_kernel<<<blks(NX / 4), 256, 0, stream>>>(x, XH, XL, (int)(NX / 4));
  split_kernel<<<blks(NWA / 4), 256, 0, stream>>>(w_attn, WAH, nullptr, (int)(NWA / 4));
  split_kernel<<<blks(NWP / 4), 256, 0, stream>>>(w_proj, WPH, WPL, (int)(NWP / 4));

  gemm_nt<0, 2><<<dim3(3 * C_EMB / 128, 4 * T_SEQ / 128), 256, 0, stream>>>(
      XH, XL, WAH, nullptr, C_EMB, QB, KB, VT, nullptr, 0);

  fa_kernel<<<dim3(T_SEQ / 128, N_BH), 256, 0, stream>>>(QB, KB, VT, YH, YL);

  gemm_nt<1, 3><<<dim3(C_EMB / 128, 4 * T_SEQ / 128), 256, 0, stream>>>(
      YH, YL, WPH, WPL, C_EMB, nullptr, nullptr, nullptr, out, C_EMB);
}

// Round 6
// 247.627 us; speedup vs baseline: 1.9026x; 1.1707x over previous
//
#include <hip/hip_runtime.h>
#include <stdint.h>

typedef unsigned short u16;
typedef uint32_t u32;
typedef __attribute__((ext_vector_type(8))) short short8;
typedef __attribute__((ext_vector_type(4))) float f32x4;
typedef __attribute__((ext_vector_type(16))) float f32x16;

static constexpr int T_SEQ = 2048;
static constexpr int C_EMB = 768;
static constexpr int N_HD  = 12;
static constexpr int D_HD  = 64;
static constexpr int N_BH  = 48;   // B * H

#define MFMA16(a, b, c) __builtin_amdgcn_mfma_f32_16x16x32_bf16((a), (b), (c), 0, 0, 0)
#define MFMA32(a, b, c) __builtin_amdgcn_mfma_f32_32x32x16_bf16((a), (b), (c), 0, 0, 0)

#if __has_builtin(__builtin_amdgcn_exp2f)
#define EXP2(x) __builtin_amdgcn_exp2f(x)
#else
#define EXP2(x) exp2f(x)
#endif

__device__ __forceinline__ u16 f2bf(float f) {
  union { float f; u32 u; } v; v.f = f;
  u32 r = v.u + 0x7FFFu + ((v.u >> 16) & 1u);   // RNE
  return (u16)(r >> 16);
}
__device__ __forceinline__ float bf2f(u16 h) {
  union { u32 u; float f; } v; v.u = ((u32)h) << 16; return v.f;
}
// pack two f32 -> u32 of 2 bf16, LOW element first — PROVEN order (rounds 1-2 passed
// feeding MFMA B-operands with exactly this packing). Replaces v_cvt_pk_bf16_f32,
// whose element order was the isolated suspect for round-5's pair-swap error.
__device__ __forceinline__ u32 pack_bf16(float lo, float hi) {
  return (u32)f2bf(lo) | ((u32)f2bf(hi) << 16);
}

__device__ __forceinline__ void gload_lds16(const void* g, void* l) {
  __builtin_amdgcn_global_load_lds((const __attribute__((address_space(1))) void*)g,
                                   (__attribute__((address_space(3))) void*)l, 16, 0, 0);
}

// XOR swizzle for [rows][64 bf16] LDS tiles (128 B rows, 8 slots of 16 B)
__device__ __forceinline__ int swz(int r, int kb) {
  return r * 128 + (kb ^ ((r & 7) << 4));
}

// ---------------- split fp32 -> bf16 hi (+ optional lo) ----------------
__global__ void split_kernel(const float* __restrict__ src, u16* __restrict__ hi,
                             u16* __restrict__ lo, int n4) {
  int i = blockIdx.x * blockDim.x + threadIdx.x;
  int stride = gridDim.x * blockDim.x;
  for (; i < n4; i += stride) {
    float4 v = ((const float4*)src)[i];
    ushort4 H;
    H.x = f2bf(v.x); H.y = f2bf(v.y); H.z = f2bf(v.z); H.w = f2bf(v.w);
    ((ushort4*)hi)[i] = H;
    if (lo) {
      ushort4 L;
      L.x = f2bf(v.x - bf2f(H.x)); L.y = f2bf(v.y - bf2f(H.y));
      L.z = f2bf(v.z - bf2f(H.z)); L.w = f2bf(v.w - bf2f(H.w));
      ((ushort4*)lo)[i] = L;
    }
  }
}

// ---------------- NT GEMM, split-bf16, 128x128 tile, BK=64 ----------------
// D[m,n] = sum_k A[m,k]*B[n,k]
// PASSES==3: aH*bH + aH*bL + aL*bH ; PASSES==2: aH*bH + aL*bH (no B-lo)
// EPI 0: QKV epilogue -> q,k bf16 [bh][t][64] (q*0.125*log2e), v transposed [bh][d][2048]
// EPI 1: fp32 write to outp
template <int EPI, int PASSES, int MINW>
__global__ __launch_bounds__(256, MINW) void gemm_nt(
    const u16* __restrict__ Ah, const u16* __restrict__ Al,
    const u16* __restrict__ Bh, const u16* __restrict__ Bl, int K,
    u16* __restrict__ qg, u16* __restrict__ kg, u16* __restrict__ vtg,
    float* __restrict__ outp, int ldout) {
  constexpr int NT = (PASSES == 2) ? 3 : 4;
  __shared__ __align__(16) char lds[NT * 16384];   // Ah | Al | Bh | [Bl]
  char* LA_h = lds;
  char* LA_l = lds + 16384;
  char* LB_h = lds + 32768;
  char* LB_l = lds + ((NT == 4) ? 49152 : 32768);
  const int tid = threadIdx.x, lane = tid & 63, w = tid >> 6;
  const int g = lane >> 4, c16 = lane & 15;
  const int wr = w >> 1, wc = w & 1;
  // XCD-chunked block swizzle (T1): nwg % 8 == 0 for both uses
  const int nwg = gridDim.x * gridDim.y;
  const int id = blockIdx.y * gridDim.x + blockIdx.x;
  const int sw = (id & 7) * (nwg >> 3) + (id >> 3);
  const int m0 = (sw / gridDim.x) * 128, n0 = (sw % gridDim.x) * 128;
  f32x4 acc[4][4] = {};

  for (int k0 = 0; k0 < K; k0 += 64) {
    __syncthreads();
#pragma unroll
    for (int tile = 0; tile < NT; tile++) {
      const u16* src = (tile == 0) ? Ah : (tile == 1) ? Al : (tile == 2) ? Bh : Bl;
      const int row0 = (tile < 2) ? m0 : n0;
      char* dst = lds + tile * 16384;
#pragma unroll
      for (int i = 0; i < 4; i++) {
        int c = tid + 256 * i;
        int r = c >> 3;
        int sp = (c & 7) ^ (r & 7);
        gload_lds16(src + (size_t)(row0 + r) * K + k0 + sp * 8,
                    dst + w * 1024 + i * 4096);
      }
    }
    __syncthreads();
#pragma unroll
    for (int ks = 0; ks < 2; ks++) {
      const int kb = ks * 64 + g * 16;
      short8 aH[4], aL[4], bH[4], bL[4];
#pragma unroll
      for (int mf = 0; mf < 4; mf++) {
        int r = wr * 64 + mf * 16 + c16;
        aH[mf] = *(const short8*)(LA_h + swz(r, kb));
        aL[mf] = *(const short8*)(LA_l + swz(r, kb));
      }
#pragma unroll
      for (int nf = 0; nf < 4; nf++) {
        int r = wc * 64 + nf * 16 + c16;
        bH[nf] = *(const short8*)(LB_h + swz(r, kb));
        if (PASSES == 3) bL[nf] = *(const short8*)(LB_l + swz(r, kb));
      }
#pragma unroll
      for (int mf = 0; mf < 4; mf++)
#pragma unroll
        for (int nf = 0; nf < 4; nf++) {
          acc[mf][nf] = MFMA16(aH[mf], bH[nf], acc[mf][nf]);
          acc[mf][nf] = MFMA16(aL[mf], bH[nf], acc[mf][nf]);
          if (PASSES == 3) acc[mf][nf] = MFMA16(aH[mf], bL[nf], acc[mf][nf]);
        }
    }
  }

#pragma unroll
  for (int mf = 0; mf < 4; mf++)
#pragma unroll
    for (int nf = 0; nf < 4; nf++) {
      if (EPI == 0) {
        int col = n0 + wc * 64 + nf * 16 + c16;
        int p = (col >= 2 * C_EMB) ? 2 : (col >= C_EMB ? 1 : 0);
        int rem = col - p * C_EMB;
        int h = rem >> 6, d = rem & 63;
        int rowb = m0 + wr * 64 + mf * 16 + g * 4;
        int b = rowb >> 11, t0 = rowb & (T_SEQ - 1);
        int bhh = b * N_HD + h;
        if (p == 2) {
          ushort4 V4;
#pragma unroll
          for (int jj = 0; jj < 4; jj++) (&V4.x)[jj] = f2bf(acc[mf][nf][jj]);
          *(ushort4*)(vtg + ((size_t)bhh * D_HD + d) * T_SEQ + t0) = V4;
        } else {
          u16* dst = (p == 0) ? qg : kg;
          // Q carries 1/sqrt(64) * log2(e) so scores are in exp2 domain
          float scl = (p == 0) ? 0.18033688f : 1.0f;
#pragma unroll
          for (int jj = 0; jj < 4; jj++)
            dst[((size_t)bhh * T_SEQ + t0 + jj) * D_HD + d] = f2bf(acc[mf][nf][jj] * scl);
        }
      } else {
#pragma unroll
        for (int jj = 0; jj < 4; jj++) {
          int row = m0 + wr * 64 + mf * 16 + g * 4 + jj;
          int col = n0 + wc * 64 + nf * 16 + c16;
          outp[(size_t)row * ldout + col] = acc[mf][nf][jj];
        }
      }
    }
}

// ---------------- flash attention: swapped QK^T, 32x32x16, fixed-offset exp2 ----------------
// grid (48 bh, 16 qb): all q-blocks of one head land on one XCD (48 % 8 == 0).
// Scores bounded in log2 units -> P = 2^s directly; softmax = P/sum(P) is
// offset-invariant; bf16/f32 are scale-invariant, so no running max or rescale.
// PV uses a PERMUTED contraction mapping: B-word (hi,j) and A-word (hi,j) both
// map to kv row psi(hi,j)=(j&3)+8*(j>>2)+4*hi (+16*q4+32*nb). Same formula on
// both operands => exact for ANY internal k-layout g (round 2's pass proves
// A-map==B-map). P fragments are pure own-register packs: no cross-lane ops.
__global__ __launch_bounds__(256, 3) void fa_kernel(
    const u16* __restrict__ qg, const u16* __restrict__ kg,
    const u16* __restrict__ vtg, u16* __restrict__ yh, u16* __restrict__ yl) {
  __shared__ __align__(16) char lds[32768];   // K[128][64] swz | V^T[64][128] swz
  char* LK = lds;
  char* LV = lds + 16384;
  const int tid = threadIdx.x, lane = tid & 63, w = tid >> 6;
  const int r31 = lane & 31, hi = lane >> 5;
  const int bh = blockIdx.x, qb = blockIdx.y;
  const size_t kvbase = (size_t)bh * T_SEQ * D_HD;

  // Q B-frags (q pre-scaled by 0.125*log2e): row = qb*128 + w*32 + r31
  const u16* qrow = qg + kvbase + (size_t)(qb * 128 + w * 32 + r31) * D_HD + hi * 8;
  short8 qf[4];
#pragma unroll
  for (int ks = 0; ks < 4; ks++) qf[ks] = *(const short8*)(qrow + ks * 16);

  f32x16 yac[2] = {};
  float lsum = 0.f;

  for (int kt = 0; kt < T_SEQ / 128; kt++) {
    const int kv0 = kt * 128;
    __syncthreads();
#pragma unroll
    for (int i = 0; i < 4; i++) {
      int c = tid + 256 * i;
      int kr = c >> 3, ksl = (c & 7) ^ (kr & 7);
      gload_lds16(kg + kvbase + (size_t)(kv0 + kr) * D_HD + ksl * 8,
                  LK + w * 1024 + i * 4096);
      int vd = c >> 4, vsl = (c & 15) ^ (vd & 15);
      gload_lds16(vtg + kvbase + (size_t)vd * T_SEQ + kv0 + vsl * 8,
                  LV + w * 1024 + i * 4096);
    }
    __syncthreads();

    // S^T = mfma(K, Q): rows kv, cols q; lane owns q = r31, kv = (r&3)+8*(r>>2)+4*hi
    f32x16 p[4];
#pragma unroll
    for (int nb = 0; nb < 4; nb++) {
      f32x16 s = {};
#pragma unroll
      for (int ks = 0; ks < 4; ks++) {
        int row = nb * 32 + r31;
        short8 kf = *(const short8*)(LK + row * 128 + (((2 * ks + hi) ^ (row & 7)) << 4));
        s = MFMA32(kf, qf[ks], s);
      }
      p[nb] = s;
    }

    // P = 2^S elementwise (no max subtraction), accumulate lane-local sum
#pragma unroll
    for (int nb = 0; nb < 4; nb++)
#pragma unroll
      for (int rr = 0; rr < 16; rr++) p[nb][rr] = EXP2(p[nb][rr]);
    {
      f32x16 t0 = p[0] + p[1];
      f32x16 t1 = p[2] + p[3];
      t0 = t0 + t1;
      float a = ((t0[0] + t0[1]) + (t0[2] + t0[3])) + ((t0[4] + t0[5]) + (t0[6] + t0[7]));
      float b = ((t0[8] + t0[9]) + (t0[10] + t0[11])) + ((t0[12] + t0[13]) + (t0[14] + t0[15]));
      lsum += a + b;
    }

    // PV with permuted k-mapping: frag(q4) words = own regs q4*8 + {0..7} packed;
    // V^T read supplies kv rows 32nb+16q4 + (j&3)+8*(j>>2)+4hi via two 8B reads
#pragma unroll
    for (int nb = 0; nb < 4; nb++) {
      u32 wd[8];
#pragma unroll
      for (int i = 0; i < 8; i++)
        wd[i] = pack_bf16(p[nb][2 * i], p[nb][2 * i + 1]);
#pragma unroll
      for (int q4 = 0; q4 < 2; q4++) {
        union { u32 u[4]; short8 s8; } pu;
        pu.u[0] = wd[q4 * 4 + 0]; pu.u[1] = wd[q4 * 4 + 1];
        pu.u[2] = wd[q4 * 4 + 2]; pu.u[3] = wd[q4 * 4 + 3];
        const int slot = 4 * nb + 2 * q4;
#pragma unroll
        for (int nd = 0; nd < 2; nd++) {
          int d = nd * 32 + r31;
          union { uint2 u2[2]; short8 s8; } vu;
          vu.u2[0] = *(const uint2*)(LV + d * 256 + ((slot ^ (d & 15)) << 4) + 8 * hi);
          vu.u2[1] = *(const uint2*)(LV + d * 256 + (((slot + 1) ^ (d & 15)) << 4) + 8 * hi);
          yac[nd] = MFMA32(vu.s8, pu.s8, yac[nd]);
        }
      }
    }
  }

  // combine the two kv-half partial sums (lane pair l, l^32 share q-column)
  lsum += __shfl_xor(lsum, 32);
  float inv = 1.0f / lsum;
  const int b = bh / N_HD, hh = bh % N_HD;
  const int t = qb * 128 + w * 32 + r31;
  const size_t ybase = ((size_t)b * T_SEQ + t) * C_EMB + hh * D_HD;
#pragma unroll
  for (int nd = 0; nd < 2; nd++)
#pragma unroll
    for (int rq = 0; rq < 4; rq++) {
      int d0 = nd * 32 + rq * 8 + hi * 4;
      ushort4 H, L;
#pragma unroll
      for (int jj = 0; jj < 4; jj++) {
        float v = yac[nd][rq * 4 + jj] * inv;
        u16 hv = f2bf(v);
        (&H.x)[jj] = hv;
        (&L.x)[jj] = f2bf(v - bf2f(hv));
      }
      *(ushort4*)(yh + ybase + d0) = H;
      *(ushort4*)(yl + ybase + d0) = L;
    }
}

// ---------------- launch ----------------
extern "C" void kernel_launch(void* const* d_in, const int* in_sizes, int n_in,
                              void* d_out, int out_size, void* d_ws, size_t ws_size,
                              hipStream_t stream) {
  (void)in_sizes; (void)n_in; (void)out_size;
  const float* x      = (const float*)d_in[0];
  const float* w_attn = (const float*)d_in[1];
  const float* w_proj = (const float*)d_in[2];
  float* out = (float*)d_out;

  const size_t NX  = (size_t)4 * T_SEQ * C_EMB;     // 6,291,456
  const size_t NWA = (size_t)3 * C_EMB * C_EMB;
  const size_t NWP = (size_t)C_EMB * C_EMB;
  const size_t NQ  = (size_t)N_BH * T_SEQ * D_HD;

  u16* ws = (u16*)d_ws;
  size_t off = 0;
  u16* XH  = ws + off; off += NX;   u16* XL  = ws + off; off += NX;
  u16* WAH = ws + off; off += NWA;
  u16* WPH = ws + off; off += NWP;  u16* WPL = ws + off; off += NWP;
  u16* QB  = ws + off; off += NQ;
  u16* KB  = ws + off; off += NQ;
  u16* VT  = ws + off; off += NQ;
  u16* YH  = ws + off; off += NX;   u16* YL  = ws + off; off += NX;
  if (ws_size < off * sizeof(u16)) return;

  auto blks = [](size_t n4) {
    size_t b = (n4 + 255) / 256; return (unsigned)(b > 2048 ? 2048 : b);
  };
  split_kernel<<<blks(NX / 4), 256, 0, stream>>>(x, XH, XL, (int)(NX / 4));
  split_kernel<<<blks(NWA / 4), 256, 0, stream>>>(w_attn, WAH, nullptr, (int)(NWA / 4));
  split_kernel<<<blks(NWP / 4), 256, 0, stream>>>(w_proj, WPH, WPL, (int)(NWP / 4));

  gemm_nt<0, 2, 3><<<dim3(3 * C_EMB / 128, 4 * T_SEQ / 128), 256, 0, stream>>>(
      XH, XL, WAH, nullptr, C_EMB, QB, KB, VT, nullptr, 0);

  fa_kernel<<<dim3(N_BH, T_SEQ / 128), 256, 0, stream>>>(QB, KB, VT, YH, YL);

  gemm_nt<1, 3, 2><<<dim3(C_EMB / 128, 4 * T_SEQ / 128), 256, 0, stream>>>(
      YH, YL, WPH, WPL, C_EMB, nullptr, nullptr, nullptr, out, C_EMB);
}

// Round 7
// 211.482 us; speedup vs baseline: 2.2277x; 1.1709x over previous
//
#include <hip/hip_runtime.h>
#include <stdint.h>

typedef unsigned short u16;
typedef uint32_t u32;
typedef __attribute__((ext_vector_type(8))) short short8;
typedef __attribute__((ext_vector_type(4))) float f32x4;
typedef __attribute__((ext_vector_type(16))) float f32x16;

static constexpr int T_SEQ = 2048;
static constexpr int C_EMB = 768;
static constexpr int N_HD  = 12;
static constexpr int D_HD  = 64;
static constexpr int N_BH  = 48;   // B * H

#define MFMA16(a, b, c) __builtin_amdgcn_mfma_f32_16x16x32_bf16((a), (b), (c), 0, 0, 0)
#define MFMA32(a, b, c) __builtin_amdgcn_mfma_f32_32x32x16_bf16((a), (b), (c), 0, 0, 0)

#if __has_builtin(__builtin_amdgcn_exp2f)
#define EXP2(x) __builtin_amdgcn_exp2f(x)
#else
#define EXP2(x) exp2f(x)
#endif

__device__ __forceinline__ u16 f2bf(float f) {
  union { float f; u32 u; } v; v.f = f;
  u32 r = v.u + 0x7FFFu + ((v.u >> 16) & 1u);   // RNE
  return (u16)(r >> 16);
}
__device__ __forceinline__ float bf2f(u16 h) {
  union { u32 u; float f; } v; v.u = ((u32)h) << 16; return v.f;
}
// pack two POSITIVE f32 -> u32 of 2 bf16 (low element = a), round-half-up.
// __byte_perm(x,y,s): result byte i = byte s.nibble[i] of {y:x} (x = bytes 0-3).
// sel 0x7632 -> [x.b2, x.b3, y.b2, y.b3] = [a_hi16 | b_hi16<<16].
__device__ __forceinline__ u32 pack2bf(float a, float b) {
  union { float f; u32 u; } x, y; x.f = a; y.f = b;
  return __byte_perm(x.u + 0x8000u, y.u + 0x8000u, 0x7632);
}

__device__ __forceinline__ void gload_lds16(const void* g, void* l) {
  __builtin_amdgcn_global_load_lds((const __attribute__((address_space(1))) void*)g,
                                   (__attribute__((address_space(3))) void*)l, 16, 0, 0);
}

// XOR swizzle for [rows][64 bf16] LDS tiles (128 B rows, 8 slots of 16 B)
__device__ __forceinline__ int swz(int r, int kb) {
  return r * 128 + (kb ^ ((r & 7) << 4));
}

// ---------------- split fp32 -> bf16 hi (+ optional lo) ----------------
__global__ void split_kernel(const float* __restrict__ src, u16* __restrict__ hi,
                             u16* __restrict__ lo, int n4) {
  int i = blockIdx.x * blockDim.x + threadIdx.x;
  int stride = gridDim.x * blockDim.x;
  for (; i < n4; i += stride) {
    float4 v = ((const float4*)src)[i];
    ushort4 H;
    H.x = f2bf(v.x); H.y = f2bf(v.y); H.z = f2bf(v.z); H.w = f2bf(v.w);
    ((ushort4*)hi)[i] = H;
    if (lo) {
      ushort4 L;
      L.x = f2bf(v.x - bf2f(H.x)); L.y = f2bf(v.y - bf2f(H.y));
      L.z = f2bf(v.z - bf2f(H.z)); L.w = f2bf(v.w - bf2f(H.w));
      ((ushort4*)lo)[i] = L;
    }
  }
}

// ---------------- NT GEMM, split-bf16, 128x128 tile, BK=64 ----------------
// D[m,n] = sum_k A[m,k]*B[n,k]
// PASSES==1: aH*bH; ==2: +aL*bH; ==3: +aH*bL
// EPI 0: QKV epilogue -> q,k bf16 [bh][t][64] (q*0.125*log2e),
//        v transposed+kv-permuted [bh][d][2048] (swap bits 2,3 of t in 16-groups)
// EPI 1: fp32 write to outp
template <int EPI, int PASSES, int MINW>
__global__ __launch_bounds__(256, MINW) void gemm_nt(
    const u16* __restrict__ Ah, const u16* __restrict__ Al,
    const u16* __restrict__ Bh, const u16* __restrict__ Bl, int K,
    u16* __restrict__ qg, u16* __restrict__ kg, u16* __restrict__ vtg,
    float* __restrict__ outp, int ldout) {
  constexpr int NA = (PASSES >= 2) ? 2 : 1;          // A-side tiles
  constexpr int NT = NA + ((PASSES == 3) ? 2 : 1);   // total tiles
  __shared__ __align__(16) char lds[NT * 16384];
  char* LA_h = lds;
  char* LA_l = lds + 16384;                 // valid iff NA==2
  char* LB_h = lds + NA * 16384;
  char* LB_l = lds + (NA + 1) * 16384;      // valid iff PASSES==3
  const int tid = threadIdx.x, lane = tid & 63, w = tid >> 6;
  const int g = lane >> 4, c16 = lane & 15;
  const int wr = w >> 1, wc = w & 1;
  // XCD-chunked block swizzle (T1): nwg % 8 == 0 for both uses
  const int nwg = gridDim.x * gridDim.y;
  const int id = blockIdx.y * gridDim.x + blockIdx.x;
  const int sw = (id & 7) * (nwg >> 3) + (id >> 3);
  const int m0 = (sw / gridDim.x) * 128, n0 = (sw % gridDim.x) * 128;
  f32x4 acc[4][4] = {};

  for (int k0 = 0; k0 < K; k0 += 64) {
    __syncthreads();
#pragma unroll
    for (int tile = 0; tile < NT; tile++) {
      const u16* src = (tile < NA) ? ((tile == 0) ? Ah : Al)
                                   : ((tile == NA) ? Bh : Bl);
      const int row0 = (tile < NA) ? m0 : n0;
      char* dst = lds + tile * 16384;
#pragma unroll
      for (int i = 0; i < 4; i++) {
        int c = tid + 256 * i;
        int r = c >> 3;
        int sp = (c & 7) ^ (r & 7);
        gload_lds16(src + (size_t)(row0 + r) * K + k0 + sp * 8,
                    dst + w * 1024 + i * 4096);
      }
    }
    __syncthreads();
#pragma unroll
    for (int ks = 0; ks < 2; ks++) {
      const int kb = ks * 64 + g * 16;
      short8 aH[4], aL[4], bH[4], bL[4];
#pragma unroll
      for (int mf = 0; mf < 4; mf++) {
        int r = wr * 64 + mf * 16 + c16;
        aH[mf] = *(const short8*)(LA_h + swz(r, kb));
        if (PASSES >= 2) aL[mf] = *(const short8*)(LA_l + swz(r, kb));
      }
#pragma unroll
      for (int nf = 0; nf < 4; nf++) {
        int r = wc * 64 + nf * 16 + c16;
        bH[nf] = *(const short8*)(LB_h + swz(r, kb));
        if (PASSES == 3) bL[nf] = *(const short8*)(LB_l + swz(r, kb));
      }
#pragma unroll
      for (int mf = 0; mf < 4; mf++)
#pragma unroll
        for (int nf = 0; nf < 4; nf++) {
          acc[mf][nf] = MFMA16(aH[mf], bH[nf], acc[mf][nf]);
          if (PASSES >= 2) acc[mf][nf] = MFMA16(aL[mf], bH[nf], acc[mf][nf]);
          if (PASSES == 3) acc[mf][nf] = MFMA16(aH[mf], bL[nf], acc[mf][nf]);
        }
    }
  }

#pragma unroll
  for (int mf = 0; mf < 4; mf++)
#pragma unroll
    for (int nf = 0; nf < 4; nf++) {
      if (EPI == 0) {
        int col = n0 + wc * 64 + nf * 16 + c16;
        int p = (col >= 2 * C_EMB) ? 2 : (col >= C_EMB ? 1 : 0);
        int rem = col - p * C_EMB;
        int h = rem >> 6, d = rem & 63;
        int rowb = m0 + wr * 64 + mf * 16 + g * 4;
        int b = rowb >> 11, t0 = rowb & (T_SEQ - 1);
        int bhh = b * N_HD + h;
        if (p == 2) {
          ushort4 V4;
#pragma unroll
          for (int jj = 0; jj < 4; jj++) (&V4.x)[jj] = f2bf(acc[mf][nf][jj]);
          // kv permutation: position(r) swaps bits 2<->3 of r within 16-groups,
          // so fa's PV fragment (slot 2kk+hi) is one contiguous b128.
          int t0p = (t0 & ~12) | ((t0 & 4) << 1) | ((t0 & 8) >> 1);
          *(ushort4*)(vtg + ((size_t)bhh * D_HD + d) * T_SEQ + t0p) = V4;
        } else {
          u16* dst = (p == 0) ? qg : kg;
          // Q carries 1/sqrt(64) * log2(e) so scores are in exp2 domain
          float scl = (p == 0) ? 0.18033688f : 1.0f;
#pragma unroll
          for (int jj = 0; jj < 4; jj++)
            dst[((size_t)bhh * T_SEQ + t0 + jj) * D_HD + d] = f2bf(acc[mf][nf][jj] * scl);
        }
      } else {
#pragma unroll
        for (int jj = 0; jj < 4; jj++) {
          int row = m0 + wr * 64 + mf * 16 + g * 4 + jj;
          int col = n0 + wc * 64 + nf * 16 + c16;
          outp[(size_t)row * ldout + col] = acc[mf][nf][jj];
        }
      }
    }
}

// ---------------- flash attention: swapped QK^T, 32x32x16, fixed-offset exp2 ----------------
// grid (48 bh, 16 qb): all q-blocks of one head land on one XCD (48 % 8 == 0).
// P = 2^s directly (scores bounded, softmax offset-invariant, bf16/f32
// scale-invariant) -> no running max, no rescale. PV contraction slot (hi,j)
// maps to kv row 16kk + (j&3)+8*(j>>2)+4*hi on BOTH operands: P words are the
// lane's own S^T accumulator registers; V^T is stored kv-permuted by the QKV
// epilogue so the A-side fragment is one b128 (same conflict class as K reads).
__global__ __launch_bounds__(256, 3) void fa_kernel(
    const u16* __restrict__ qg, const u16* __restrict__ kg,
    const u16* __restrict__ vtg, u16* __restrict__ yh, u16* __restrict__ yl) {
  __shared__ __align__(16) char lds[32768];   // K[128][64] swz | V^T[64][128] swz
  char* LK = lds;
  char* LV = lds + 16384;
  const int tid = threadIdx.x, lane = tid & 63, w = tid >> 6;
  const int r31 = lane & 31, hi = lane >> 5;
  const int bh = blockIdx.x, qb = blockIdx.y;
  const size_t kvbase = (size_t)bh * T_SEQ * D_HD;

  // Q B-frags (q pre-scaled by 0.125*log2e): row = qb*128 + w*32 + r31
  const u16* qrow = qg + kvbase + (size_t)(qb * 128 + w * 32 + r31) * D_HD + hi * 8;
  short8 qf[4];
#pragma unroll
  for (int ks = 0; ks < 4; ks++) qf[ks] = *(const short8*)(qrow + ks * 16);

  // precomputed LDS read addresses (XOR fields are bit-disjoint, so
  // ((2k+hi)^e)<<4 = ((k^(e>>1))<<5) | ((hi^(e&1))<<4) folds per-lane)
  const int eK = r31 & 7, eV = r31 & 15;
  const char* pK[4];
#pragma unroll
  for (int ks = 0; ks < 4; ks++)
    pK[ks] = LK + r31 * 128 + ((hi ^ (eK & 1)) << 4) + (((ks << 5) ^ ((eK >> 1) << 5)));
  const char* pV[2][8];
#pragma unroll
  for (int nd = 0; nd < 2; nd++)
#pragma unroll
    for (int kk = 0; kk < 8; kk++)
      pV[nd][kk] = LV + (nd * 32 + r31) * 256 + ((hi ^ (eV & 1)) << 4) +
                   (((kk << 5) ^ ((eV >> 1) << 5)));

  f32x16 yac[2] = {};
  f32x16 lacc = {};

  for (int kt = 0; kt < T_SEQ / 128; kt++) {
    const int kv0 = kt * 128;
    __syncthreads();
#pragma unroll
    for (int i = 0; i < 4; i++) {
      int c = tid + 256 * i;
      int kr = c >> 3, ksl = (c & 7) ^ (kr & 7);
      gload_lds16(kg + kvbase + (size_t)(kv0 + kr) * D_HD + ksl * 8,
                  LK + w * 1024 + i * 4096);
      int vd = c >> 4, vsl = (c & 15) ^ (vd & 15);
      gload_lds16(vtg + kvbase + (size_t)vd * T_SEQ + kv0 + vsl * 8,
                  LV + w * 1024 + i * 4096);
    }
    __syncthreads();

    // S^T = mfma(K, Q): rows kv, cols q; lane owns q = r31, kv = (r&3)+8*(r>>2)+4*hi
    f32x16 p[4];
#pragma unroll
    for (int nb = 0; nb < 4; nb++) {
      f32x16 s = {};
#pragma unroll
      for (int ks = 0; ks < 4; ks++) {
        short8 kf = *(const short8*)(pK[ks] + nb * 4096);
        s = MFMA32(kf, qf[ks], s);
      }
      p[nb] = s;
    }

    // P = 2^S elementwise; accumulate sum vector-wise (horizontal reduce once at end)
#pragma unroll
    for (int nb = 0; nb < 4; nb++)
#pragma unroll
      for (int rr = 0; rr < 16; rr++) p[nb][rr] = EXP2(p[nb][rr]);
    lacc += (p[0] + p[1]) + (p[2] + p[3]);

    // PV: P frag = own-register packs; V frag = single b128 (kv-permuted store)
#pragma unroll
    for (int nb = 0; nb < 4; nb++) {
      u32 wd[8];
#pragma unroll
      for (int i = 0; i < 8; i++)
        wd[i] = pack2bf(p[nb][2 * i], p[nb][2 * i + 1]);
#pragma unroll
      for (int q4 = 0; q4 < 2; q4++) {
        union { u32 u[4]; short8 s8; } pu;
        pu.u[0] = wd[q4 * 4 + 0]; pu.u[1] = wd[q4 * 4 + 1];
        pu.u[2] = wd[q4 * 4 + 2]; pu.u[3] = wd[q4 * 4 + 3];
        const int kk = nb * 2 + q4;
#pragma unroll
        for (int nd = 0; nd < 2; nd++) {
          short8 vf = *(const short8*)(pV[nd][kk]);
          yac[nd] = MFMA32(vf, pu.s8, yac[nd]);
        }
      }
    }
  }

  // horizontal reduce of lacc, then combine the two kv-half partials
  float lsum;
  {
    float a = ((lacc[0] + lacc[1]) + (lacc[2] + lacc[3])) +
              ((lacc[4] + lacc[5]) + (lacc[6] + lacc[7]));
    float b = ((lacc[8] + lacc[9]) + (lacc[10] + lacc[11])) +
              ((lacc[12] + lacc[13]) + (lacc[14] + lacc[15]));
    lsum = a + b;
  }
  lsum += __shfl_xor(lsum, 32);
  float inv = 1.0f / lsum;
  const int b = bh / N_HD, hh = bh % N_HD;
  const int t = qb * 128 + w * 32 + r31;
  const size_t ybase = ((size_t)b * T_SEQ + t) * C_EMB + hh * D_HD;
#pragma unroll
  for (int nd = 0; nd < 2; nd++)
#pragma unroll
    for (int rq = 0; rq < 4; rq++) {
      int d0 = nd * 32 + rq * 8 + hi * 4;
      ushort4 H, L;
#pragma unroll
      for (int jj = 0; jj < 4; jj++) {
        float v = yac[nd][rq * 4 + jj] * inv;
        u16 hv = f2bf(v);
        (&H.x)[jj] = hv;
        (&L.x)[jj] = f2bf(v - bf2f(hv));
      }
      *(ushort4*)(yh + ybase + d0) = H;
      *(ushort4*)(yl + ybase + d0) = L;
    }
}

// ---------------- launch ----------------
extern "C" void kernel_launch(void* const* d_in, const int* in_sizes, int n_in,
                              void* d_out, int out_size, void* d_ws, size_t ws_size,
                              hipStream_t stream) {
  (void)in_sizes; (void)n_in; (void)out_size;
  const float* x      = (const float*)d_in[0];
  const float* w_attn = (const float*)d_in[1];
  const float* w_proj = (const float*)d_in[2];
  float* out = (float*)d_out;

  const size_t NX  = (size_t)4 * T_SEQ * C_EMB;     // 6,291,456
  const size_t NWA = (size_t)3 * C_EMB * C_EMB;
  const size_t NWP = (size_t)C_EMB * C_EMB;
  const size_t NQ  = (size_t)N_BH * T_SEQ * D_HD;

  u16* ws = (u16*)d_ws;
  size_t off = 0;
  u16* XH  = ws + off; off += NX;
  u16* WAH = ws + off; off += NWA;
  u16* WPH = ws + off; off += NWP;  u16* WPL = ws + off; off += NWP;
  u16* QB  = ws + off; off += NQ;
  u16* KB  = ws + off; off += NQ;
  u16* VT  = ws + off; off += NQ;
  u16* YH  = ws + off; off += NX;   u16* YL  = ws + off; off += NX;
  if (ws_size < off * sizeof(u16)) return;

  auto blks = [](size_t n4) {
    size_t b = (n4 + 255) / 256; return (unsigned)(b > 2048 ? 2048 : b);
  };
  split_kernel<<<blks(NX / 4), 256, 0, stream>>>(x, XH, nullptr, (int)(NX / 4));
  split_kernel<<<blks(NWA / 4), 256, 0, stream>>>(w_attn, WAH, nullptr, (int)(NWA / 4));
  split_kernel<<<blks(NWP / 4), 256, 0, stream>>>(w_proj, WPH, WPL, (int)(NWP / 4));

  gemm_nt<0, 1, 3><<<dim3(3 * C_EMB / 128, 4 * T_SEQ / 128), 256, 0, stream>>>(
      XH, nullptr, WAH, nullptr, C_EMB, QB, KB, VT, nullptr, 0);

  fa_kernel<<<dim3(N_BH, T_SEQ / 128), 256, 0, stream>>>(QB, KB, VT, YH, YL);

  gemm_nt<1, 3, 2><<<dim3(C_EMB / 128, 4 * T_SEQ / 128), 256, 0, stream>>>(
      YH, YL, WPH, WPL, C_EMB, nullptr, nullptr, nullptr, out, C_EMB);
}

// Round 8
// 205.082 us; speedup vs baseline: 2.2973x; 1.0312x over previous
//
#include <hip/hip_runtime.h>
#include <stdint.h>

typedef unsigned short u16;
typedef uint32_t u32;
typedef __attribute__((ext_vector_type(8))) short short8;
typedef _Float16 half8 __attribute__((ext_vector_type(8)));
typedef __attribute__((ext_vector_type(4))) float f32x4;
typedef __attribute__((ext_vector_type(16))) float f32x16;

static constexpr int T_SEQ = 2048;
static constexpr int C_EMB = 768;
static constexpr int N_HD  = 12;
static constexpr int D_HD  = 64;
static constexpr int N_BH  = 48;   // B * H

#define MFMA16B(a, b, c) __builtin_amdgcn_mfma_f32_16x16x32_bf16((a), (b), (c), 0, 0, 0)
#define MFMA32B(a, b, c) __builtin_amdgcn_mfma_f32_32x32x16_bf16((a), (b), (c), 0, 0, 0)

__device__ __forceinline__ f32x4 mfma16f(short8 a, short8 b, f32x4 c) {
  return __builtin_amdgcn_mfma_f32_16x16x32_f16(
      __builtin_bit_cast(half8, a), __builtin_bit_cast(half8, b), c, 0, 0, 0);
}
__device__ __forceinline__ f32x16 mfma32f(short8 a, short8 b, f32x16 c) {
  return __builtin_amdgcn_mfma_f32_32x32x16_f16(
      __builtin_bit_cast(half8, a), __builtin_bit_cast(half8, b), c, 0, 0, 0);
}

#if __has_builtin(__builtin_amdgcn_exp2f)
#define EXP2(x) __builtin_amdgcn_exp2f(x)
#else
#define EXP2(x) exp2f(x)
#endif

__device__ __forceinline__ u16 f2bf(float f) {
  union { float f; u32 u; } v; v.f = f;
  u32 r = v.u + 0x7FFFu + ((v.u >> 16) & 1u);   // RNE
  return (u16)(r >> 16);
}
__device__ __forceinline__ float bf2f(u16 h) {
  union { u32 u; float f; } v; v.u = ((u32)h) << 16; return v.f;
}
__device__ __forceinline__ u16 f2h(float f) {
  union { _Float16 h; u16 u; } v; v.h = (_Float16)f; return v.u;   // v_cvt_f16_f32 RNE
}
// pack two POSITIVE f32 -> u32 of 2 bf16 (low element = a), round-half-up. PROVEN (r6/7).
__device__ __forceinline__ u32 pack2bf(float a, float b) {
  union { float f; u32 u; } x, y; x.f = a; y.f = b;
  return __byte_perm(x.u + 0x8000u, y.u + 0x8000u, 0x7632);
}

__device__ __forceinline__ void gload_lds16(const void* g, void* l) {
  __builtin_amdgcn_global_load_lds((const __attribute__((address_space(1))) void*)g,
                                   (__attribute__((address_space(3))) void*)l, 16, 0, 0);
}

// XOR swizzle for [rows][64 elems of 2B] LDS tiles (128 B rows, 8 slots of 16 B)
__device__ __forceinline__ int swz(int r, int kb) {
  return r * 128 + (kb ^ ((r & 7) << 4));
}

// ---------------- fused fp32 -> f16 conversion of x, w_attn, w_proj ----------------
__global__ void cvt3_f16(const float* __restrict__ x, const float* __restrict__ wa,
                         const float* __restrict__ wp, u16* __restrict__ xf,
                         u16* __restrict__ waf, u16* __restrict__ wpf,
                         int n0, int n1, int n2) {
  int i = blockIdx.x * blockDim.x + threadIdx.x;
  int st = gridDim.x * blockDim.x;
  int ntot = n0 + n1 + n2;
  for (; i < ntot; i += st) {
    const float* s; u16* d; int j = i;
    if (j < n0) { s = x; d = xf; }
    else if (j < n0 + n1) { j -= n0; s = wa; d = waf; }
    else { j -= n0 + n1; s = wp; d = wpf; }
    float4 v = ((const float4*)s)[j];
    ushort4 o;
    o.x = f2h(v.x); o.y = f2h(v.y); o.z = f2h(v.z); o.w = f2h(v.w);
    ((ushort4*)d)[j] = o;
  }
}

// ---------------- NT GEMM, f16 single-pass, 128x128 tile, BK=64 ----------------
// D[m,n] = sum_k A[m,k]*B[n,k], A/B f16.
// EPI 0: QKV epilogue -> q,k f16 [bh][t][64] (q*0.125*log2e),
//        v bf16 transposed+kv-permuted [bh][d][2048]
// EPI 1: fp32 write to outp
template <int EPI, int MINW>
__global__ __launch_bounds__(256, MINW) void gemm_nt(
    const u16* __restrict__ Ah, const u16* __restrict__ Bh, int K,
    u16* __restrict__ qg, u16* __restrict__ kg, u16* __restrict__ vtg,
    float* __restrict__ outp, int ldout) {
  __shared__ __align__(16) char lds[2 * 16384];   // A | B tiles, each 128x64 f16
  char* LA = lds;
  char* LB = lds + 16384;
  const int tid = threadIdx.x, lane = tid & 63, w = tid >> 6;
  const int g = lane >> 4, c16 = lane & 15;
  const int wr = w >> 1, wc = w & 1;
  // XCD-chunked block swizzle (T1): nwg % 8 == 0 for both uses
  const int nwg = gridDim.x * gridDim.y;
  const int id = blockIdx.y * gridDim.x + blockIdx.x;
  const int sw = (id & 7) * (nwg >> 3) + (id >> 3);
  const int m0 = (sw / gridDim.x) * 128, n0 = (sw % gridDim.x) * 128;
  f32x4 acc[4][4] = {};

  for (int k0 = 0; k0 < K; k0 += 64) {
    __syncthreads();
#pragma unroll
    for (int tile = 0; tile < 2; tile++) {
      const u16* src = (tile == 0) ? Ah : Bh;
      const int row0 = (tile == 0) ? m0 : n0;
      char* dst = lds + tile * 16384;
#pragma unroll
      for (int i = 0; i < 4; i++) {
        int c = tid + 256 * i;
        int r = c >> 3;
        int sp = (c & 7) ^ (r & 7);
        gload_lds16(src + (size_t)(row0 + r) * K + k0 + sp * 8,
                    dst + w * 1024 + i * 4096);
      }
    }
    __syncthreads();
#pragma unroll
    for (int ks = 0; ks < 2; ks++) {
      const int kb = ks * 64 + g * 16;
      short8 aF[4], bF[4];
#pragma unroll
      for (int mf = 0; mf < 4; mf++)
        aF[mf] = *(const short8*)(LA + swz(wr * 64 + mf * 16 + c16, kb));
#pragma unroll
      for (int nf = 0; nf < 4; nf++)
        bF[nf] = *(const short8*)(LB + swz(wc * 64 + nf * 16 + c16, kb));
#pragma unroll
      for (int mf = 0; mf < 4; mf++)
#pragma unroll
        for (int nf = 0; nf < 4; nf++)
          acc[mf][nf] = mfma16f(aF[mf], bF[nf], acc[mf][nf]);
    }
  }

#pragma unroll
  for (int mf = 0; mf < 4; mf++)
#pragma unroll
    for (int nf = 0; nf < 4; nf++) {
      if (EPI == 0) {
        int col = n0 + wc * 64 + nf * 16 + c16;
        int p = (col >= 2 * C_EMB) ? 2 : (col >= C_EMB ? 1 : 0);
        int rem = col - p * C_EMB;
        int h = rem >> 6, d = rem & 63;
        int rowb = m0 + wr * 64 + mf * 16 + g * 4;
        int b = rowb >> 11, t0 = rowb & (T_SEQ - 1);
        int bhh = b * N_HD + h;
        if (p == 2) {
          ushort4 V4;
#pragma unroll
          for (int jj = 0; jj < 4; jj++) (&V4.x)[jj] = f2bf(acc[mf][nf][jj]);
          // kv permutation: swap bits 2<->3 of t within 16-groups so fa's PV
          // fragment (slot 2kk+hi) is one contiguous b128.
          int t0p = (t0 & ~12) | ((t0 & 4) << 1) | ((t0 & 8) >> 1);
          *(ushort4*)(vtg + ((size_t)bhh * D_HD + d) * T_SEQ + t0p) = V4;
        } else {
          u16* dst = (p == 0) ? qg : kg;
          // Q carries 1/sqrt(64) * log2(e) so scores are in exp2 domain
          float scl = (p == 0) ? 0.18033688f : 1.0f;
#pragma unroll
          for (int jj = 0; jj < 4; jj++)
            dst[((size_t)bhh * T_SEQ + t0 + jj) * D_HD + d] = f2h(acc[mf][nf][jj] * scl);
        }
      } else {
#pragma unroll
        for (int jj = 0; jj < 4; jj++) {
          int row = m0 + wr * 64 + mf * 16 + g * 4 + jj;
          int col = n0 + wc * 64 + nf * 16 + c16;
          outp[(size_t)row * ldout + col] = acc[mf][nf][jj];
        }
      }
    }
}

// ---------------- flash attention: swapped QK^T (f16), PV (bf16), fixed-offset exp2 ----
// grid (48 bh, 16 qb): all q-blocks of one head land on one XCD (48 % 8 == 0).
// P = 2^s directly (scores bounded, softmax offset-invariant, bf16/f32
// scale-invariant) -> no running max, no rescale. P spans ~2^±30 so P/V stay
// bf16 (f16 would overflow); q/k are f16 for 8x less score-input noise.
__global__ __launch_bounds__(256, 3) void fa_kernel(
    const u16* __restrict__ qg, const u16* __restrict__ kg,
    const u16* __restrict__ vtg, u16* __restrict__ yf) {
  __shared__ __align__(16) char lds[32768];   // K[128][64] swz | V^T[64][128] swz
  char* LK = lds;
  char* LV = lds + 16384;
  const int tid = threadIdx.x, lane = tid & 63, w = tid >> 6;
  const int r31 = lane & 31, hi = lane >> 5;
  const int bh = blockIdx.x, qb = blockIdx.y;
  const size_t kvbase = (size_t)bh * T_SEQ * D_HD;

  // Q B-frags (q pre-scaled by 0.125*log2e): row = qb*128 + w*32 + r31
  const u16* qrow = qg + kvbase + (size_t)(qb * 128 + w * 32 + r31) * D_HD + hi * 8;
  short8 qf[4];
#pragma unroll
  for (int ks = 0; ks < 4; ks++) qf[ks] = *(const short8*)(qrow + ks * 16);

  // precomputed LDS read addresses (XOR fields are bit-disjoint)
  const int eK = r31 & 7, eV = r31 & 15;
  const char* pK[4];
#pragma unroll
  for (int ks = 0; ks < 4; ks++)
    pK[ks] = LK + r31 * 128 + ((hi ^ (eK & 1)) << 4) + (((ks << 5) ^ ((eK >> 1) << 5)));
  const char* pV[2][8];
#pragma unroll
  for (int nd = 0; nd < 2; nd++)
#pragma unroll
    for (int kk = 0; kk < 8; kk++)
      pV[nd][kk] = LV + (nd * 32 + r31) * 256 + ((hi ^ (eV & 1)) << 4) +
                   (((kk << 5) ^ ((eV >> 1) << 5)));

  f32x16 yac[2] = {};
  f32x16 lacc = {};

  for (int kt = 0; kt < T_SEQ / 128; kt++) {
    const int kv0 = kt * 128;
    __syncthreads();
#pragma unroll
    for (int i = 0; i < 4; i++) {
      int c = tid + 256 * i;
      int kr = c >> 3, ksl = (c & 7) ^ (kr & 7);
      gload_lds16(kg + kvbase + (size_t)(kv0 + kr) * D_HD + ksl * 8,
                  LK + w * 1024 + i * 4096);
      int vd = c >> 4, vsl = (c & 15) ^ (vd & 15);
      gload_lds16(vtg + kvbase + (size_t)vd * T_SEQ + kv0 + vsl * 8,
                  LV + w * 1024 + i * 4096);
    }
    __syncthreads();

    // S^T = mfma(K, Q) in f16: rows kv, cols q; lane owns q = r31
    f32x16 p[4];
#pragma unroll
    for (int nb = 0; nb < 4; nb++) {
      f32x16 s = {};
#pragma unroll
      for (int ks = 0; ks < 4; ks++) {
        short8 kf = *(const short8*)(pK[ks] + nb * 4096);
        s = mfma32f(kf, qf[ks], s);
      }
      p[nb] = s;
    }

    // P = 2^S elementwise; accumulate sum vector-wise
#pragma unroll
    for (int nb = 0; nb < 4; nb++)
#pragma unroll
      for (int rr = 0; rr < 16; rr++) p[nb][rr] = EXP2(p[nb][rr]);
    lacc += (p[0] + p[1]) + (p[2] + p[3]);

    // PV (bf16): P frag = own-register packs; V frag = single b128 (kv-permuted)
#pragma unroll
    for (int nb = 0; nb < 4; nb++) {
      u32 wd[8];
#pragma unroll
      for (int i = 0; i < 8; i++)
        wd[i] = pack2bf(p[nb][2 * i], p[nb][2 * i + 1]);
#pragma unroll
      for (int q4 = 0; q4 < 2; q4++) {
        union { u32 u[4]; short8 s8; } pu;
        pu.u[0] = wd[q4 * 4 + 0]; pu.u[1] = wd[q4 * 4 + 1];
        pu.u[2] = wd[q4 * 4 + 2]; pu.u[3] = wd[q4 * 4 + 3];
        const int kk = nb * 2 + q4;
#pragma unroll
        for (int nd = 0; nd < 2; nd++) {
          short8 vf = *(const short8*)(pV[nd][kk]);
          yac[nd] = MFMA32B(vf, pu.s8, yac[nd]);
        }
      }
    }
  }

  // horizontal reduce of lacc, then combine the two kv-half partials
  float lsum;
  {
    float a = ((lacc[0] + lacc[1]) + (lacc[2] + lacc[3])) +
              ((lacc[4] + lacc[5]) + (lacc[6] + lacc[7]));
    float b = ((lacc[8] + lacc[9]) + (lacc[10] + lacc[11])) +
              ((lacc[12] + lacc[13]) + (lacc[14] + lacc[15]));
    lsum = a + b;
  }
  lsum += __shfl_xor(lsum, 32);
  float inv = 1.0f / lsum;
  const int b = bh / N_HD, hh = bh % N_HD;
  const int t = qb * 128 + w * 32 + r31;
  const size_t ybase = ((size_t)b * T_SEQ + t) * C_EMB + hh * D_HD;
#pragma unroll
  for (int nd = 0; nd < 2; nd++)
#pragma unroll
    for (int rq = 0; rq < 4; rq++) {
      int d0 = nd * 32 + rq * 8 + hi * 4;
      ushort4 H;
#pragma unroll
      for (int jj = 0; jj < 4; jj++)
        (&H.x)[jj] = f2h(yac[nd][rq * 4 + jj] * inv);
      *(ushort4*)(yf + ybase + d0) = H;
    }
}

// ---------------- launch ----------------
extern "C" void kernel_launch(void* const* d_in, const int* in_sizes, int n_in,
                              void* d_out, int out_size, void* d_ws, size_t ws_size,
                              hipStream_t stream) {
  (void)in_sizes; (void)n_in; (void)out_size;
  const float* x      = (const float*)d_in[0];
  const float* w_attn = (const float*)d_in[1];
  const float* w_proj = (const float*)d_in[2];
  float* out = (float*)d_out;

  const size_t NX  = (size_t)4 * T_SEQ * C_EMB;     // 6,291,456
  const size_t NWA = (size_t)3 * C_EMB * C_EMB;
  const size_t NWP = (size_t)C_EMB * C_EMB;
  const size_t NQ  = (size_t)N_BH * T_SEQ * D_HD;

  u16* ws = (u16*)d_ws;
  size_t off = 0;
  u16* XF  = ws + off; off += NX;    // f16
  u16* WAF = ws + off; off += NWA;   // f16
  u16* WPF = ws + off; off += NWP;   // f16
  u16* QF  = ws + off; off += NQ;    // f16
  u16* KF  = ws + off; off += NQ;    // f16
  u16* VT  = ws + off; off += NQ;    // bf16
  u16* YF  = ws + off; off += NX;    // f16
  if (ws_size < off * sizeof(u16)) return;

  {
    int n0 = (int)(NX / 4), n1 = (int)(NWA / 4), n2 = (int)(NWP / 4);
    size_t b = ((size_t)(n0 + n1 + n2) + 255) / 256;
    unsigned nb = (unsigned)(b > 2048 ? 2048 : b);
    cvt3_f16<<<nb, 256, 0, stream>>>(x, w_attn, w_proj, XF, WAF, WPF, n0, n1, n2);
  }

  gemm_nt<0, 3><<<dim3(3 * C_EMB / 128, 4 * T_SEQ / 128), 256, 0, stream>>>(
      XF, WAF, C_EMB, QF, KF, VT, nullptr, 0);

  fa_kernel<<<dim3(N_BH, T_SEQ / 128), 256, 0, stream>>>(QF, KF, VT, YF);

  gemm_nt<1, 3><<<dim3(C_EMB / 128, 4 * T_SEQ / 128), 256, 0, stream>>>(
      YF, WPF, C_EMB, nullptr, nullptr, nullptr, out, C_EMB);
}

// Round 9
// 201.528 us; speedup vs baseline: 2.3378x; 1.0176x over previous
//
#include <hip/hip_runtime.h>
#include <stdint.h>

typedef unsigned short u16;
typedef uint32_t u32;
typedef __attribute__((ext_vector_type(8))) short short8;
typedef _Float16 half8 __attribute__((ext_vector_type(8)));
typedef __attribute__((ext_vector_type(4))) float f32x4;
typedef __attribute__((ext_vector_type(16))) float f32x16;

static constexpr int T_SEQ = 2048;
static constexpr int C_EMB = 768;
static constexpr int N_HD  = 12;
static constexpr int D_HD  = 64;
static constexpr int N_BH  = 48;   // B * H

#define MFMA32B(a, b, c) __builtin_amdgcn_mfma_f32_32x32x16_bf16((a), (b), (c), 0, 0, 0)

__device__ __forceinline__ f32x4 mfma16f(short8 a, short8 b, f32x4 c) {
  return __builtin_amdgcn_mfma_f32_16x16x32_f16(
      __builtin_bit_cast(half8, a), __builtin_bit_cast(half8, b), c, 0, 0, 0);
}
__device__ __forceinline__ f32x16 mfma32f(short8 a, short8 b, f32x16 c) {
  return __builtin_amdgcn_mfma_f32_32x32x16_f16(
      __builtin_bit_cast(half8, a), __builtin_bit_cast(half8, b), c, 0, 0, 0);
}

#if __has_builtin(__builtin_amdgcn_exp2f)
#define EXP2(x) __builtin_amdgcn_exp2f(x)
#else
#define EXP2(x) exp2f(x)
#endif

__device__ __forceinline__ u16 f2bf(float f) {
  union { float f; u32 u; } v; v.f = f;
  u32 r = v.u + 0x7FFFu + ((v.u >> 16) & 1u);   // RNE
  return (u16)(r >> 16);
}
__device__ __forceinline__ float bf2f(u16 h) {
  union { u32 u; float f; } v; v.u = ((u32)h) << 16; return v.f;
}
__device__ __forceinline__ u16 f2h(float f) {
  union { _Float16 h; u16 u; } v; v.h = (_Float16)f; return v.u;   // v_cvt_f16_f32 RNE
}
// pack two POSITIVE f32 -> u32 of 2 bf16 (low element = a), round-half-up. PROVEN (r6/7).
__device__ __forceinline__ u32 pack2bf(float a, float b) {
  union { float f; u32 u; } x, y; x.f = a; y.f = b;
  return __byte_perm(x.u + 0x8000u, y.u + 0x8000u, 0x7632);
}

__device__ __forceinline__ void gload_lds16(const void* g, void* l) {
  __builtin_amdgcn_global_load_lds((const __attribute__((address_space(1))) void*)g,
                                   (__attribute__((address_space(3))) void*)l, 16, 0, 0);
}

// XOR swizzle for [rows][64 elems of 2B] LDS tiles (128 B rows, 8 slots of 16 B)
__device__ __forceinline__ int swz(int r, int kb) {
  return r * 128 + (kb ^ ((r & 7) << 4));
}

// ---------------- fused fp32 -> f16 conversion of x, w_attn, w_proj ----------------
__global__ void cvt3_f16(const float* __restrict__ x, const float* __restrict__ wa,
                         const float* __restrict__ wp, u16* __restrict__ xf,
                         u16* __restrict__ waf, u16* __restrict__ wpf,
                         int n0, int n1, int n2) {
  int i = blockIdx.x * blockDim.x + threadIdx.x;
  int st = gridDim.x * blockDim.x;
  int ntot = n0 + n1 + n2;
  for (; i < ntot; i += st) {
    const float* s; u16* d; int j = i;
    if (j < n0) { s = x; d = xf; }
    else if (j < n0 + n1) { j -= n0; s = wa; d = waf; }
    else { j -= n0 + n1; s = wp; d = wpf; }
    float4 v = ((const float4*)s)[j];
    ushort4 o;
    o.x = f2h(v.x); o.y = f2h(v.y); o.z = f2h(v.z); o.w = f2h(v.w);
    ((ushort4*)d)[j] = o;
  }
}

// ---------------- NT GEMM, f16 single-pass, 128x128 tile, BK=64 ----------------
// T3-minimal 2-phase pipeline: double-buffered LDS; issue next K-step's
// global_load_lds BEFORE computing current from the other buffer; ONE barrier
// per K-step (its implicit vmcnt(0)+lgkmcnt(0) drain is the synchronization).
// Race-free: end-of-iter barrier means all waves finished reading buf[t&1]
// before anyone overwrites it at iter t+2.
// EPI 0: QKV epilogue -> q,k f16 [bh][t][64] (q*0.125*log2e),
//        v bf16 transposed+kv-permuted [bh][d][2048]
// EPI 1: fp32 write to outp
template <int EPI>
__global__ __launch_bounds__(256, 2) void gemm_nt(
    const u16* __restrict__ Ah, const u16* __restrict__ Bh, int K,
    u16* __restrict__ qg, u16* __restrict__ kg, u16* __restrict__ vtg,
    float* __restrict__ outp, int ldout) {
  __shared__ __align__(16) char lds[2 * 2 * 16384];   // [buf][A|B], 128x64 f16 each
  const int tid = threadIdx.x, lane = tid & 63, w = tid >> 6;
  const int g = lane >> 4, c16 = lane & 15;
  const int wr = w >> 1, wc = w & 1;
  // XCD-chunked block swizzle (T1): nwg % 8 == 0 for both uses
  const int nwg = gridDim.x * gridDim.y;
  const int id = blockIdx.y * gridDim.x + blockIdx.x;
  const int sw = (id & 7) * (nwg >> 3) + (id >> 3);
  const int m0 = (sw / gridDim.x) * 128, n0 = (sw % gridDim.x) * 128;
  f32x4 acc[4][4] = {};

  // per-thread staging geometry (fixed across steps)
  const int sr  = (tid * 2) >> 4;          // row pair base: c = tid + 256*i -> r = c>>3
  // stage one K-step's A+B tiles into buffer `cur`
  auto STAGE = [&](int cur, int k0) {
#pragma unroll
    for (int tile = 0; tile < 2; tile++) {
      const u16* src = (tile == 0) ? Ah : Bh;
      const int row0 = (tile == 0) ? m0 : n0;
      char* dst = lds + cur * 32768 + tile * 16384;
#pragma unroll
      for (int i = 0; i < 4; i++) {
        int c = tid + 256 * i;
        int r = c >> 3;
        int sp = (c & 7) ^ (r & 7);
        gload_lds16(src + (size_t)(row0 + r) * K + k0 + sp * 8,
                    dst + w * 1024 + i * 4096);
      }
    }
  };

  const int NKT = K >> 6;
  STAGE(0, 0);
  __syncthreads();                       // drains vmcnt(0): buf0 ready
  for (int t = 0; t < NKT; t++) {
    const int cur = t & 1;
    if (t + 1 < NKT) STAGE(cur ^ 1, (t + 1) << 6);   // prefetch under compute
    const char* LA = lds + cur * 32768;
    const char* LB = lds + cur * 32768 + 16384;
#pragma unroll
    for (int ks = 0; ks < 2; ks++) {
      const int kb = ks * 64 + g * 16;
      short8 aF[4], bF[4];
#pragma unroll
      for (int mf = 0; mf < 4; mf++)
        aF[mf] = *(const short8*)(LA + swz(wr * 64 + mf * 16 + c16, kb));
#pragma unroll
      for (int nf = 0; nf < 4; nf++)
        bF[nf] = *(const short8*)(LB + swz(wc * 64 + nf * 16 + c16, kb));
#pragma unroll
      for (int mf = 0; mf < 4; mf++)
#pragma unroll
        for (int nf = 0; nf < 4; nf++)
          acc[mf][nf] = mfma16f(aF[mf], bF[nf], acc[mf][nf]);
    }
    __syncthreads();                     // all reads of buf[cur] done; next buf ready
  }

#pragma unroll
  for (int mf = 0; mf < 4; mf++)
#pragma unroll
    for (int nf = 0; nf < 4; nf++) {
      if (EPI == 0) {
        int col = n0 + wc * 64 + nf * 16 + c16;
        int p = (col >= 2 * C_EMB) ? 2 : (col >= C_EMB ? 1 : 0);
        int rem = col - p * C_EMB;
        int h = rem >> 6, d = rem & 63;
        int rowb = m0 + wr * 64 + mf * 16 + g * 4;
        int b = rowb >> 11, t0 = rowb & (T_SEQ - 1);
        int bhh = b * N_HD + h;
        if (p == 2) {
          ushort4 V4;
#pragma unroll
          for (int jj = 0; jj < 4; jj++) (&V4.x)[jj] = f2bf(acc[mf][nf][jj]);
          // kv permutation: swap bits 2<->3 of t within 16-groups so fa's PV
          // fragment (slot 2kk+hi) is one contiguous b128.
          int t0p = (t0 & ~12) | ((t0 & 4) << 1) | ((t0 & 8) >> 1);
          *(ushort4*)(vtg + ((size_t)bhh * D_HD + d) * T_SEQ + t0p) = V4;
        } else {
          u16* dst = (p == 0) ? qg : kg;
          // Q carries 1/sqrt(64) * log2(e) so scores are in exp2 domain
          float scl = (p == 0) ? 0.18033688f : 1.0f;
#pragma unroll
          for (int jj = 0; jj < 4; jj++)
            dst[((size_t)bhh * T_SEQ + t0 + jj) * D_HD + d] = f2h(acc[mf][nf][jj] * scl);
        }
      } else {
#pragma unroll
        for (int jj = 0; jj < 4; jj++) {
          int row = m0 + wr * 64 + mf * 16 + g * 4 + jj;
          int col = n0 + wc * 64 + nf * 16 + c16;
          outp[(size_t)row * ldout + col] = acc[mf][nf][jj];
        }
      }
    }
}

// ---------------- flash attention: swapped QK^T (f16), PV (bf16), fixed-offset exp2 ----
// grid (48 bh, 16 qb): all q-blocks of one head land on one XCD (48 % 8 == 0).
// P = 2^s directly (scores bounded, softmax offset-invariant, bf16/f32
// scale-invariant) -> no running max, no rescale. P spans ~2^±30 so P/V stay
// bf16 (f16 would overflow); q/k are f16 for 8x less score-input noise.
__global__ __launch_bounds__(256, 3) void fa_kernel(
    const u16* __restrict__ qg, const u16* __restrict__ kg,
    const u16* __restrict__ vtg, u16* __restrict__ yf) {
  __shared__ __align__(16) char lds[32768];   // K[128][64] swz | V^T[64][128] swz
  char* LK = lds;
  char* LV = lds + 16384;
  const int tid = threadIdx.x, lane = tid & 63, w = tid >> 6;
  const int r31 = lane & 31, hi = lane >> 5;
  const int bh = blockIdx.x, qb = blockIdx.y;
  const size_t kvbase = (size_t)bh * T_SEQ * D_HD;

  // Q B-frags (q pre-scaled by 0.125*log2e): row = qb*128 + w*32 + r31
  const u16* qrow = qg + kvbase + (size_t)(qb * 128 + w * 32 + r31) * D_HD + hi * 8;
  short8 qf[4];
#pragma unroll
  for (int ks = 0; ks < 4; ks++) qf[ks] = *(const short8*)(qrow + ks * 16);

  // precomputed LDS read addresses (XOR fields are bit-disjoint)
  const int eK = r31 & 7, eV = r31 & 15;
  const char* pK[4];
#pragma unroll
  for (int ks = 0; ks < 4; ks++)
    pK[ks] = LK + r31 * 128 + ((hi ^ (eK & 1)) << 4) + (((ks << 5) ^ ((eK >> 1) << 5)));
  const char* pV[2][8];
#pragma unroll
  for (int nd = 0; nd < 2; nd++)
#pragma unroll
    for (int kk = 0; kk < 8; kk++)
      pV[nd][kk] = LV + (nd * 32 + r31) * 256 + ((hi ^ (eV & 1)) << 4) +
                   (((kk << 5) ^ ((eV >> 1) << 5)));

  f32x16 yac[2] = {};
  f32x16 lacc = {};

  for (int kt = 0; kt < T_SEQ / 128; kt++) {
    const int kv0 = kt * 128;
    __syncthreads();
#pragma unroll
    for (int i = 0; i < 4; i++) {
      int c = tid + 256 * i;
      int kr = c >> 3, ksl = (c & 7) ^ (kr & 7);
      gload_lds16(kg + kvbase + (size_t)(kv0 + kr) * D_HD + ksl * 8,
                  LK + w * 1024 + i * 4096);
      int vd = c >> 4, vsl = (c & 15) ^ (vd & 15);
      gload_lds16(vtg + kvbase + (size_t)vd * T_SEQ + kv0 + vsl * 8,
                  LV + w * 1024 + i * 4096);
    }
    __syncthreads();

    // S^T = mfma(K, Q) in f16: rows kv, cols q; lane owns q = r31
    f32x16 p[4];
#pragma unroll
    for (int nb = 0; nb < 4; nb++) {
      f32x16 s = {};
#pragma unroll
      for (int ks = 0; ks < 4; ks++) {
        short8 kf = *(const short8*)(pK[ks] + nb * 4096);
        s = mfma32f(kf, qf[ks], s);
      }
      p[nb] = s;
    }

    // P = 2^S elementwise; accumulate sum vector-wise
#pragma unroll
    for (int nb = 0; nb < 4; nb++)
#pragma unroll
      for (int rr = 0; rr < 16; rr++) p[nb][rr] = EXP2(p[nb][rr]);
    lacc += (p[0] + p[1]) + (p[2] + p[3]);

    // PV (bf16): P frag = own-register packs; V frag = single b128 (kv-permuted)
#pragma unroll
    for (int nb = 0; nb < 4; nb++) {
      u32 wd[8];
#pragma unroll
      for (int i = 0; i < 8; i++)
        wd[i] = pack2bf(p[nb][2 * i], p[nb][2 * i + 1]);
#pragma unroll
      for (int q4 = 0; q4 < 2; q4++) {
        union { u32 u[4]; short8 s8; } pu;
        pu.u[0] = wd[q4 * 4 + 0]; pu.u[1] = wd[q4 * 4 + 1];
        pu.u[2] = wd[q4 * 4 + 2]; pu.u[3] = wd[q4 * 4 + 3];
        const int kk = nb * 2 + q4;
#pragma unroll
        for (int nd = 0; nd < 2; nd++) {
          short8 vf = *(const short8*)(pV[nd][kk]);
          yac[nd] = MFMA32B(vf, pu.s8, yac[nd]);
        }
      }
    }
  }

  // horizontal reduce of lacc, then combine the two kv-half partials
  float lsum;
  {
    float a = ((lacc[0] + lacc[1]) + (lacc[2] + lacc[3])) +
              ((lacc[4] + lacc[5]) + (lacc[6] + lacc[7]));
    float b = ((lacc[8] + lacc[9]) + (lacc[10] + lacc[11])) +
              ((lacc[12] + lacc[13]) + (lacc[14] + lacc[15]));
    lsum = a + b;
  }
  lsum += __shfl_xor(lsum, 32);
  float inv = 1.0f / lsum;
  const int b = bh / N_HD, hh = bh % N_HD;
  const int t = qb * 128 + w * 32 + r31;
  const size_t ybase = ((size_t)b * T_SEQ + t) * C_EMB + hh * D_HD;
#pragma unroll
  for (int nd = 0; nd < 2; nd++)
#pragma unroll
    for (int rq = 0; rq < 4; rq++) {
      int d0 = nd * 32 + rq * 8 + hi * 4;
      ushort4 H;
#pragma unroll
      for (int jj = 0; jj < 4; jj++)
        (&H.x)[jj] = f2h(yac[nd][rq * 4 + jj] * inv);
      *(ushort4*)(yf + ybase + d0) = H;
    }
}

// ---------------- launch ----------------
extern "C" void kernel_launch(void* const* d_in, const int* in_sizes, int n_in,
                              void* d_out, int out_size, void* d_ws, size_t ws_size,
                              hipStream_t stream) {
  (void)in_sizes; (void)n_in; (void)out_size;
  const float* x      = (const float*)d_in[0];
  const float* w_attn = (const float*)d_in[1];
  const float* w_proj = (const float*)d_in[2];
  float* out = (float*)d_out;

  const size_t NX  = (size_t)4 * T_SEQ * C_EMB;     // 6,291,456
  const size_t NWA = (size_t)3 * C_EMB * C_EMB;
  const size_t NWP = (size_t)C_EMB * C_EMB;
  const size_t NQ  = (size_t)N_BH * T_SEQ * D_HD;

  u16* ws = (u16*)d_ws;
  size_t off = 0;
  u16* XF  = ws + off; off += NX;    // f16
  u16* WAF = ws + off; off += NWA;   // f16
  u16* WPF = ws + off; off += NWP;   // f16
  u16* QF  = ws + off; off += NQ;    // f16
  u16* KF  = ws + off; off += NQ;    // f16
  u16* VT  = ws + off; off += NQ;    // bf16
  u16* YF  = ws + off; off += NX;    // f16
  if (ws_size < off * sizeof(u16)) return;

  {
    int n0 = (int)(NX / 4), n1 = (int)(NWA / 4), n2 = (int)(NWP / 4);
    size_t b = ((size_t)(n0 + n1 + n2) + 255) / 256;
    unsigned nb = (unsigned)(b > 2048 ? 2048 : b);
    cvt3_f16<<<nb, 256, 0, stream>>>(x, w_attn, w_proj, XF, WAF, WPF, n0, n1, n2);
  }

  gemm_nt<0><<<dim3(3 * C_EMB / 128, 4 * T_SEQ / 128), 256, 0, stream>>>(
      XF, WAF, C_EMB, QF, KF, VT, nullptr, 0);

  fa_kernel<<<dim3(N_BH, T_SEQ / 128), 256, 0, stream>>>(QF, KF, VT, YF);

  gemm_nt<1><<<dim3(C_EMB / 128, 4 * T_SEQ / 128), 256, 0, stream>>>(
      YF, WPF, C_EMB, nullptr, nullptr, nullptr, out, C_EMB);
}